// Round 12
// baseline (39729.657 us; speedup 1.0000x reference)
//
#include <hip/hip_runtime.h>
#include <math.h>

#define D_MODEL 1024
#define NHEADS 16
#define DHEAD 64
#define NLAYERS 12
#define VOCAB 32000
#define BATCH 8
#define SEQ 512
#define NTOK (BATCH*SEQ)   // 4096

using short8 = __attribute__((ext_vector_type(8))) short;
using fx4    = __attribute__((ext_vector_type(4))) float;

#define GLL16(g, l) __builtin_amdgcn_global_load_lds( \
    (const __attribute__((address_space(1))) unsigned int*)(g), \
    (__attribute__((address_space(3))) unsigned int*)(l), 16, 0, 0)

__device__ __forceinline__ unsigned short f2bf(float f) {
  union { float f; unsigned u; } v; v.f = f;
  unsigned r = v.u + 0x7FFFu + ((v.u >> 16) & 1u);
  return (unsigned short)(r >> 16);
}
__device__ __forceinline__ float bf2f(unsigned short u) {
  union { unsigned u; float f; } v; v.u = ((unsigned)u) << 16;
  return v.f;
}
__device__ __forceinline__ void split2(float x, unsigned short& h, unsigned short& l) {
  h = f2bf(x);
  l = f2bf(x - bf2f(h));
}
__device__ __forceinline__ float gelu_exact(float x) {
  return 0.5f * x * (1.f + erff(x * 0.70710678118654752f));
}

// ---------------- weight conversion (hi/lo split planes) ----------------

__global__ __launch_bounds__(256) void cvt_qkv_split(const float* __restrict__ WQ,
    const float* __restrict__ WK, const float* __restrict__ WV,
    unsigned short* __restrict__ out)
{
  const long total = 12L * 3072 * 256;     // float4 units
  const long stride = (long)gridDim.x * blockDim.x;
  for (long t = (long)blockIdx.x * blockDim.x + threadIdx.x; t < total; t += stride) {
    const long layer = t / (3072L * 256);
    const long rem = t - layer * (3072L * 256);
    const int n = (int)(rem >> 8);
    const int k4 = (int)(rem & 255);
    const float* src;
    if (n < 1024)       src = WQ + ((size_t)layer * 1024 + n) * 1024;
    else if (n < 2048)  src = WK + ((size_t)layer * 1024 + (n - 1024)) * 1024;
    else                src = WV + ((size_t)layer * 1024 + (n - 2048)) * 1024;
    const float4 v = *(const float4*)(src + k4 * 4);
    ushort4 h, l; unsigned short a, b;
    split2(v.x, a, b); h.x = a; l.x = b;
    split2(v.y, a, b); h.y = a; l.y = b;
    split2(v.z, a, b); h.z = a; l.z = b;
    split2(v.w, a, b); h.w = a; l.w = b;
    unsigned short* dst = out + ((size_t)layer * 3072 + n) * 2048 + k4 * 4;
    *(ushort4*)dst = h;
    *(ushort4*)(dst + 1024) = l;
  }
}

__global__ __launch_bounds__(256) void cvt_split(const float* __restrict__ in,
    unsigned short* __restrict__ out, long rows, int K)
{
  const int K4 = K >> 2;
  const long total = rows * K4;
  const long stride = (long)gridDim.x * blockDim.x;
  for (long t = (long)blockIdx.x * blockDim.x + threadIdx.x; t < total; t += stride) {
    const long r = t / K4;
    const int k4 = (int)(t - r * K4);
    const float4 v = *(const float4*)(in + r * K + k4 * 4);
    ushort4 h, l; unsigned short a, b;
    split2(v.x, a, b); h.x = a; l.x = b;
    split2(v.y, a, b); h.y = a; l.y = b;
    split2(v.z, a, b); h.z = a; l.z = b;
    split2(v.w, a, b); h.w = a; l.w = b;
    unsigned short* dst = out + r * 2 * K + k4 * 4;
    *(ushort4*)dst = h;
    *(ushort4*)(dst + K) = l;
  }
}

__global__ __launch_bounds__(256) void transpose_cvt_split(const float* __restrict__ in,
    unsigned short* __restrict__ out, int R, int C)
{
  __shared__ float tile[32][33];
  in  += (size_t)blockIdx.z * R * C;
  out += (size_t)blockIdx.z * 2 * R * C;
  const int r0 = blockIdx.y * 32, c0 = blockIdx.x * 32;
  const int tr = threadIdx.x >> 5, tc = threadIdx.x & 31;
#pragma unroll
  for (int i = 0; i < 4; ++i)
    tile[tr + i * 8][tc] = in[(size_t)(r0 + tr + i * 8) * C + c0 + tc];
  __syncthreads();
#pragma unroll
  for (int i = 0; i < 4; ++i) {
    unsigned short h, l;
    split2(tile[tc][tr + i * 8], h, l);
    const size_t o = (size_t)(c0 + tr + i * 8) * 2 * R + r0 + tc;
    out[o] = h;
    out[o + R] = l;
  }
}

__global__ __launch_bounds__(256) void transpose_cvt(const float* __restrict__ in,
    unsigned short* __restrict__ out, int R, int C)
{
  __shared__ float tile[32][33];
  const int r0 = blockIdx.y * 32, c0 = blockIdx.x * 32;
  const int tr = threadIdx.x >> 5, tc = threadIdx.x & 31;
#pragma unroll
  for (int i = 0; i < 4; ++i)
    tile[tr + i * 8][tc] = in[(size_t)(r0 + tr + i * 8) * C + c0 + tc];
  __syncthreads();
#pragma unroll
  for (int i = 0; i < 4; ++i)
    out[(size_t)(c0 + tr + i * 8) * R + r0 + tc] = f2bf(tile[tc][tr + i * 8]);
}

// ---------------- embedding + positional ----------------

__global__ __launch_bounds__(256) void embed_kernel(const int* __restrict__ ids,
    const float* __restrict__ Wv, float* __restrict__ x)
{
  const int t = blockIdx.x;
  const int id = ids[t];
  const int l = t & (SEQ - 1);
  const float pos = (float)l;
  const int d0 = threadIdx.x * 4;
  const float i0 = (float)(d0 >> 1);
  const float f0 = expf(-0.017988946039016f * i0);
  const float f1 = expf(-0.017988946039016f * (i0 + 1.f));
  const float a0 = pos * f0, a1 = pos * f1;
  float4 v;
  v.x = Wv[(size_t)(d0 + 0) * VOCAB + id] + sinf(a0);
  v.y = Wv[(size_t)(d0 + 1) * VOCAB + id] + cosf(a0);
  v.z = Wv[(size_t)(d0 + 2) * VOCAB + id] + sinf(a1);
  v.w = Wv[(size_t)(d0 + 3) * VOCAB + id] + cosf(a1);
  ((float4*)(x + (size_t)t * 1024))[threadIdx.x] = v;
}

// ---------------- layernorm (f32 in -> hi/lo bf16 planes out, stride 2048) ----------------

__global__ __launch_bounds__(256) void layernorm_split(const float* __restrict__ x,
    const float* __restrict__ g, const float* __restrict__ be,
    unsigned short* __restrict__ out)
{
  const int row = blockIdx.x;
  const float4 v = ((const float4*)(x + (size_t)row * 1024))[threadIdx.x];
  float s = v.x + v.y + v.z + v.w;
  float q = v.x * v.x + v.y * v.y + v.z * v.z + v.w * v.w;
#pragma unroll
  for (int o = 32; o; o >>= 1) { s += __shfl_xor(s, o); q += __shfl_xor(q, o); }
  __shared__ float ss[4], qq[4];
  const int w = threadIdx.x >> 6;
  if ((threadIdx.x & 63) == 0) { ss[w] = s; qq[w] = q; }
  __syncthreads();
  s = ss[0] + ss[1] + ss[2] + ss[3];
  q = qq[0] + qq[1] + qq[2] + qq[3];
  const float mean = s * (1.f / 1024.f);
  const float var = q * (1.f / 1024.f) - mean * mean;
  const float rstd = rsqrtf(var + 1e-5f);
  const float4 gv = ((const float4*)g)[threadIdx.x];
  const float4 bv = ((const float4*)be)[threadIdx.x];
  float4 y;
  y.x = (v.x - mean) * rstd * gv.x + bv.x;
  y.y = (v.y - mean) * rstd * gv.y + bv.y;
  y.z = (v.z - mean) * rstd * gv.z + bv.z;
  y.w = (v.w - mean) * rstd * gv.w + bv.w;
  ushort4 h4, l4; unsigned short a, b;
  split2(y.x, a, b); h4.x = a; l4.x = b;
  split2(y.y, a, b); h4.y = a; l4.y = b;
  split2(y.z, a, b); h4.z = a; l4.z = b;
  split2(y.w, a, b); h4.w = a; l4.w = b;
  unsigned short* dst = out + (size_t)row * 2048 + threadIdx.x * 4;
  *(ushort4*)dst = h4;
  *(ushort4*)(dst + 1024) = l4;
}

// ---------------- split GEMM: C[M,N] = A[M,K] * B[N,K]^T, near-f32 precision ----------------
// global_load_lds width-16 staging + XOR slot-swizzle (linear LDS dest, pre-swizzled
// global source, swizzled read). SWAPG=1: brow = blockIdx.x (fast axis) so consecutive
// blocks share the same B-panel -> L2 reuse (devocab: B=65.5MB was re-fetched 32x).

template<int EPI, int SPLIT, int SWAPG>
__global__ __launch_bounds__(256) void gemm_bt(
    const unsigned short* __restrict__ A, const unsigned short* __restrict__ B,
    float* __restrict__ Cf, unsigned short* __restrict__ Cb,
    const float* __restrict__ bias, const float* __restrict__ res,
    int M, int N, int K)
{
  __shared__ __align__(16) unsigned short As[128 * 64];
  __shared__ __align__(16) unsigned short Bs[128 * 64];
  const int tid = threadIdx.x;
  const int lane = tid & 63, w = tid >> 6;
  const int wr = w >> 1, wc = w & 1;
  const int bxi = SWAPG ? blockIdx.y : blockIdx.x;
  const int byi = SWAPG ? blockIdx.x : blockIdx.y;
  const int brow = byi * 128, bcol = bxi * 128;

  const int SA = 2 * K;                         // A always hi/lo
  const int SB = (SPLIT == 3) ? 2 * K : K;
  const int KEFF = SPLIT * K;
  fx4 acc[4][4];
  const fx4 zero = {0.f, 0.f, 0.f, 0.f};
#pragma unroll
  for (int i = 0; i < 4; ++i)
#pragma unroll
    for (int j = 0; j < 4; ++j) acc[i][j] = zero;

  const unsigned short* Ab = A + (size_t)brow * SA;
  const unsigned short* Bb = B + (size_t)bcol * SB;

  for (int k0 = 0; k0 < KEFF; k0 += 64) {
    int ka, kb;
    if (SPLIT == 3) {
      ka = (k0 < 2 * K) ? k0 : k0 - 2 * K;      // hi | lo | hi
      kb = (k0 < K) ? k0 : k0 - K;              // hi | hi | lo
    } else {
      ka = k0;                                  // hi | lo
      kb = (k0 < K) ? k0 : k0 - K;              // hi | hi
    }
    const unsigned short* Aseg = Ab + ka;
    const unsigned short* Bseg = Bb + kb;
#pragma unroll
    for (int it = 0; it < 4; ++it) {
      const int idx = it * 256 + tid;          // 0..1023
      const int r = idx >> 3;                  // tile row 0..127
      // source slot pre-swizzled so LDS slot (r, s) holds global slot s^(r&7)
      const int c = ((idx & 7) ^ (r & 7)) * 8; // col in shorts
      GLL16(&Aseg[(size_t)r * SA + c], &As[idx * 8]);
      GLL16(&Bseg[(size_t)r * SB + c], &Bs[idx * 8]);
    }
    __syncthreads();   // drains vmcnt (global_load_lds) before ds_read
#pragma unroll
    for (int kk = 0; kk < 2; ++kk) {
      short8 af[4], bfv[4];
      // logical slot for this lane: kk*4 + (lane>>4); swizzle with row parity (= lane&7)
      const int slot = ((kk * 4 + (lane >> 4)) ^ (lane & 7)) * 8;
#pragma unroll
      for (int f = 0; f < 4; ++f)
        af[f] = *(const short8*)&As[(wr * 64 + f * 16 + (lane & 15)) * 64 + slot];
#pragma unroll
      for (int f = 0; f < 4; ++f)
        bfv[f] = *(const short8*)&Bs[(wc * 64 + f * 16 + (lane & 15)) * 64 + slot];
#pragma unroll
      for (int i = 0; i < 4; ++i)
#pragma unroll
        for (int j = 0; j < 4; ++j)
          acc[i][j] = __builtin_amdgcn_mfma_f32_16x16x32_bf16(af[i], bfv[j], acc[i][j], 0, 0, 0);
    }
    __syncthreads();
  }

  // C/D layout: col = lane&15, row = (lane>>4)*4 + reg
  const int r0 = brow + wr * 64 + (lane >> 4) * 4;
  const int c0 = bcol + wc * 64 + (lane & 15);
#pragma unroll
  for (int i = 0; i < 4; ++i) {
#pragma unroll
    for (int j = 0; j < 4; ++j) {
      const int cc = c0 + j * 16;
#pragma unroll
      for (int qi = 0; qi < 4; ++qi) {
        const int rr = r0 + i * 16 + qi;
        const size_t off = (size_t)rr * N + cc;
        const float val = acc[i][j][qi];
        if (EPI == 0) {
          Cf[off] = val;
        } else if (EPI == 2) {
          Cf[off] = res[off] + val;
        } else if (EPI == 3) {
          unsigned short hh, ll;
          split2(gelu_exact(val + bias[cc]), hh, ll);
          Cb[(size_t)rr * (2 * N) + cc] = hh;
          Cb[(size_t)rr * (2 * N) + N + cc] = ll;
        } else {
          Cf[off] = res[off] + val + bias[cc];
        }
      }
    }
  }
}

// ---------------- attention v5: barrier-free, no K staging ----------------
// S = 30*tanh(qk/8) bounded -> fixed-base softmax (no max tracking, round 8 insight).
// grid.x = B*H*16 ; block = 256 (4 waves); block owns 32 rows, wave owns 8.
// q_lds/p_lds are WAVE-PRIVATE -> zero block barriers; waves run fully async.
// K rows read directly from global per-lane (L2-resident: 128KB/head); V coalesced.
// kq chunked 2x8 f4 to cap VGPR (~100 peak).
// qkvf: [NTOK][3072] f32 (q|k|v). out2: [NTOK][2048] bf16 hi|lo planes.

__global__ __launch_bounds__(256, 4) void attn_kernel(
    const float* __restrict__ qkvf,
    const int* __restrict__ amask,
    unsigned short* __restrict__ out2)
{
  const int bid = blockIdx.x;
  const int rt = 15 - (bid & 15);          // heavy causal tiles dispatch first
  const int h  = (bid >> 4) & 15;
  const int b  = bid >> 8;
  const int row0 = rt * 32;

  __shared__ __align__(16) float q_lds[4][8][64];   // [wave][rowk][d]  (wave-private)
  __shared__ __align__(16) float p_lds[4][8][64];   // [wave][rowk][key] (wave-private)

  const int tid = threadIdx.x, lane = tid & 63, w = tid >> 6;
  const size_t base = (size_t)b * SEQ;

  // hoist q rows for this wave into LDS (written and read only by this wave)
#pragma unroll
  for (int k = 0; k < 8; ++k) {
    const int l = row0 + w * 8 + k;
    q_lds[w][k][lane] = qkvf[(base + l) * 3072 + h * 64 + lane];
  }

  float sum_p[8], acc_s[8];
#pragma unroll
  for (int k = 0; k < 8; ++k) { sum_p[k] = 0.f; acc_s[k] = 0.f; }

  const int nhv = (row0 >> 6) + 1;         // 64-key halves covering 0..row0+31
  for (int hf = 0; hf < nhv; ++hf) {
    const int hs = hf << 6;
    const int key = hs + lane;

    // ---- Phase A: scores -> p (lane = key), K direct from global (L2) ----
    {
      float s_acc[8];
#pragma unroll
      for (int k = 0; k < 8; ++k) s_acc[k] = 0.f;
      const float* kp = &qkvf[(base + key) * 3072 + 1024 + h * 64];
#pragma unroll
      for (int cc = 0; cc < 2; ++cc) {
        float4 kq[8];
#pragma unroll
        for (int c4 = 0; c4 < 8; ++c4)
          kq[c4] = *(const float4*)(kp + cc * 32 + c4 * 4);
#pragma unroll
        for (int k = 0; k < 8; ++k) {
          float4 sv = {0.f, 0.f, 0.f, 0.f};
#pragma unroll
          for (int c4 = 0; c4 < 8; ++c4) {
            const float4 qv = *(const float4*)&q_lds[w][k][cc * 32 + c4 * 4];
            sv.x += kq[c4].x * qv.x; sv.y += kq[c4].y * qv.y;
            sv.z += kq[c4].z * qv.z; sv.w += kq[c4].w * qv.w;
          }
          s_acc[k] += (sv.x + sv.y) + (sv.z + sv.w);
        }
      }
      const int am = amask[b * SEQ + key];
#pragma unroll
      for (int k = 0; k < 8; ++k) {
        const int l = row0 + w * 8 + k;
        // 30*tanh(s/8) via e = exp(s/4); NaN-safe at +-inf
        const float e = __expf(s_acc[k] * 0.25f);
        const float S = 30.f - 60.f / (e + 1.f);
        float p = __expf(S);
        p = ((key <= l) && (am != 0)) ? p : 0.f;
        sum_p[k] += p;
        p_lds[w][k][lane] = p;
      }
    }

    // ---- Phase B: PV (lane = d), 32 keys at a time to cap VGPR ----
#pragma unroll
    for (int half32 = 0; half32 < 2; ++half32) {
      float vv[32];
#pragma unroll
      for (int j = 0; j < 32; ++j)
        vv[j] = qkvf[(base + hs + half32 * 32 + j) * 3072 + 2048 + h * 64 + lane];
#pragma unroll
      for (int k = 0; k < 8; ++k) {
        float a0 = 0.f, a1 = 0.f, a2 = 0.f, a3 = 0.f;
#pragma unroll
        for (int i4 = 0; i4 < 8; ++i4) {
          const float4 p4 = *(const float4*)&p_lds[w][k][half32 * 32 + i4 * 4];
          a0 += p4.x * vv[i4 * 4 + 0];
          a1 += p4.y * vv[i4 * 4 + 1];
          a2 += p4.z * vv[i4 * 4 + 2];
          a3 += p4.w * vv[i4 * 4 + 3];
        }
        acc_s[k] += (a0 + a1) + (a2 + a3);
      }
    }
  }

  // final: one shuffle-reduce per row for the softmax denominator
#pragma unroll
  for (int k = 0; k < 8; ++k) {
    float cs = sum_p[k];
#pragma unroll
    for (int o = 32; o; o >>= 1) cs += __shfl_xor(cs, o);
    const int l = row0 + w * 8 + k;
    const float o = acc_s[k] / cs;
    unsigned short hh, ll;
    split2(o, hh, ll);
    out2[(base + l) * 2048 + h * 64 + lane] = hh;
    out2[(base + l) * 2048 + 1024 + h * 64 + lane] = ll;
  }
}

extern "C" void kernel_launch(void* const* d_in, const int* in_sizes, int n_in,
                              void* d_out, int out_size, void* d_ws, size_t ws_size,
                              hipStream_t stream) {
  const int*   ids       = (const int*)d_in[0];
  const int*   amask     = (const int*)d_in[1];
  const float* W_vocab   = (const float*)d_in[2];
  const float* W_devocab = (const float*)d_in[3];
  const float* WQ        = (const float*)d_in[4];
  const float* WK        = (const float*)d_in[5];
  const float* WV        = (const float*)d_in[6];
  const float* W_O       = (const float*)d_in[7];
  const float* gamma1    = (const float*)d_in[8];
  const float* beta1     = (const float*)d_in[9];
  const float* gamma2    = (const float*)d_in[10];
  const float* beta2     = (const float*)d_in[11];
  const float* W_up      = (const float*)d_in[12];
  const float* b_up      = (const float*)d_in[13];
  const float* W_down    = (const float*)d_in[14];
  const float* b_down    = (const float*)d_in[15];
  const float* gamma_f   = (const float*)d_in[16];
  const float* beta_f    = (const float*)d_in[17];

  char* p = (char*)d_ws;
  auto alloc = [&](size_t bytes) { char* r = p; p += (bytes + 255) & ~(size_t)255; return r; };

  unsigned short* WQKV2 = (unsigned short*)alloc((size_t)NLAYERS * 3072 * 2048 * 2);
  unsigned short* WO2   = (unsigned short*)alloc((size_t)NLAYERS * 1024 * 2048 * 2);
  unsigned short* WUp2  = (unsigned short*)alloc((size_t)NLAYERS * 4096 * 2048 * 2);
  unsigned short* WDn2  = (unsigned short*)alloc((size_t)NLAYERS * 1024 * 8192 * 2);
  unsigned short* WDev1 = (unsigned short*)alloc((size_t)VOCAB * 1024 * 2);
  float* x    = (float*)alloc((size_t)NTOK * 1024 * 4);
  float* z1   = (float*)alloc((size_t)NTOK * 1024 * 4);
  unsigned short* u2    = (unsigned short*)alloc((size_t)NTOK * 2048 * 2);   // also v1 / xf
  float* qkvf = (float*)alloc((size_t)NTOK * 3072 * 4);
  unsigned short* attn2 = (unsigned short*)alloc((size_t)NTOK * 2048 * 2);
  unsigned short* h2    = (unsigned short*)alloc((size_t)NTOK * 8192 * 2);
  (void)ws_size; (void)in_sizes; (void)n_in; (void)out_size;

  // ---- weight prep (hi/lo split planes) ----
  cvt_qkv_split<<<2048, 256, 0, stream>>>(WQ, WK, WV, WQKV2);
  cvt_split<<<2048, 256, 0, stream>>>(W_O, WO2, (long)NLAYERS * 1024, 1024);
  transpose_cvt_split<<<dim3(4096 / 32, 1024 / 32, NLAYERS), 256, 0, stream>>>(W_up, WUp2, 1024, 4096);
  transpose_cvt_split<<<dim3(1024 / 32, 4096 / 32, NLAYERS), 256, 0, stream>>>(W_down, WDn2, 4096, 1024);
  transpose_cvt<<<dim3(VOCAB / 32, 1024 / 32, 1), 256, 0, stream>>>(W_devocab, WDev1, 1024, VOCAB);

  // ---- embedding ----
  embed_kernel<<<NTOK, 256, 0, stream>>>(ids, W_vocab, x);

  // ---- layers ----
  for (int l = 0; l < NLAYERS; ++l) {
    layernorm_split<<<NTOK, 256, 0, stream>>>(x, gamma1 + l * 1024, beta1 + l * 1024, u2);
    // fused QKV (split-3, f32 out): [4096,3072]
    gemm_bt<0, 3, 0><<<dim3(3072 / 128, NTOK / 128), 256, 0, stream>>>(
        u2, WQKV2 + (size_t)l * 3072 * 2048, qkvf, nullptr, nullptr, nullptr,
        NTOK, 3072, 1024);
    attn_kernel<<<BATCH * NHEADS * 16, 256, 0, stream>>>(qkvf, amask, attn2);
    // z1 = x + attn @ W_O^T
    gemm_bt<2, 3, 0><<<dim3(1024 / 128, NTOK / 128), 256, 0, stream>>>(
        attn2, WO2 + (size_t)l * 1024 * 2048, z1, nullptr, nullptr, x,
        NTOK, 1024, 1024);
    layernorm_split<<<NTOK, 256, 0, stream>>>(z1, gamma2 + l * 1024, beta2 + l * 1024, u2);
    // h = gelu(v1 @ W_up + b_up), hi/lo out
    gemm_bt<3, 3, 0><<<dim3(4096 / 128, NTOK / 128), 256, 0, stream>>>(
        u2, WUp2 + (size_t)l * 4096 * 2048, nullptr, h2, b_up + l * 4096, nullptr,
        NTOK, 4096, 1024);
    // x = z1 + h @ W_down + b_down
    gemm_bt<4, 3, 0><<<dim3(1024 / 128, NTOK / 128), 256, 0, stream>>>(
        h2, WDn2 + (size_t)l * 1024 * 8192, x, nullptr, b_down + l * 1024, z1,
        NTOK, 1024, 4096);
  }

  // ---- final LN + devocab (split-2: x hi/lo, W hi only; brow-major grid for B reuse) ----
  layernorm_split<<<NTOK, 256, 0, stream>>>(x, gamma_f, beta_f, u2);
  gemm_bt<0, 2, 1><<<dim3(NTOK / 128, VOCAB / 128), 256, 0, stream>>>(
      u2, WDev1, (float*)d_out, nullptr, nullptr, nullptr,
      NTOK, VOCAB, 1024);
}

// Round 13
// 9360.277 us; speedup vs baseline: 4.2445x; 4.2445x over previous
//
#include <hip/hip_runtime.h>
#include <math.h>

#define D_MODEL 1024
#define NHEADS 16
#define DHEAD 64
#define NLAYERS 12
#define VOCAB 32000
#define BATCH 8
#define SEQ 512
#define NTOK (BATCH*SEQ)   // 4096

using short8 = __attribute__((ext_vector_type(8))) short;
using fx4    = __attribute__((ext_vector_type(4))) float;

#define GLL16(g, l) __builtin_amdgcn_global_load_lds( \
    (const __attribute__((address_space(1))) unsigned int*)(g), \
    (__attribute__((address_space(3))) unsigned int*)(l), 16, 0, 0)

__device__ __forceinline__ unsigned short f2bf(float f) {
  union { float f; unsigned u; } v; v.f = f;
  unsigned r = v.u + 0x7FFFu + ((v.u >> 16) & 1u);
  return (unsigned short)(r >> 16);
}
__device__ __forceinline__ float bf2f(unsigned short u) {
  union { unsigned u; float f; } v; v.u = ((unsigned)u) << 16;
  return v.f;
}
__device__ __forceinline__ void split2(float x, unsigned short& h, unsigned short& l) {
  h = f2bf(x);
  l = f2bf(x - bf2f(h));
}
__device__ __forceinline__ float gelu_exact(float x) {
  return 0.5f * x * (1.f + erff(x * 0.70710678118654752f));
}

// ---------------- weight conversion (hi/lo split planes) ----------------

__global__ __launch_bounds__(256) void cvt_qkv_split(const float* __restrict__ WQ,
    const float* __restrict__ WK, const float* __restrict__ WV,
    unsigned short* __restrict__ out)
{
  const long total = 12L * 3072 * 256;     // float4 units
  const long stride = (long)gridDim.x * blockDim.x;
  for (long t = (long)blockIdx.x * blockDim.x + threadIdx.x; t < total; t += stride) {
    const long layer = t / (3072L * 256);
    const long rem = t - layer * (3072L * 256);
    const int n = (int)(rem >> 8);
    const int k4 = (int)(rem & 255);
    const float* src;
    if (n < 1024)       src = WQ + ((size_t)layer * 1024 + n) * 1024;
    else if (n < 2048)  src = WK + ((size_t)layer * 1024 + (n - 1024)) * 1024;
    else                src = WV + ((size_t)layer * 1024 + (n - 2048)) * 1024;
    const float4 v = *(const float4*)(src + k4 * 4);
    ushort4 h, l; unsigned short a, b;
    split2(v.x, a, b); h.x = a; l.x = b;
    split2(v.y, a, b); h.y = a; l.y = b;
    split2(v.z, a, b); h.z = a; l.z = b;
    split2(v.w, a, b); h.w = a; l.w = b;
    unsigned short* dst = out + ((size_t)layer * 3072 + n) * 2048 + k4 * 4;
    *(ushort4*)dst = h;
    *(ushort4*)(dst + 1024) = l;
  }
}

__global__ __launch_bounds__(256) void cvt_split(const float* __restrict__ in,
    unsigned short* __restrict__ out, long rows, int K)
{
  const int K4 = K >> 2;
  const long total = rows * K4;
  const long stride = (long)gridDim.x * blockDim.x;
  for (long t = (long)blockIdx.x * blockDim.x + threadIdx.x; t < total; t += stride) {
    const long r = t / K4;
    const int k4 = (int)(t - r * K4);
    const float4 v = *(const float4*)(in + r * K + k4 * 4);
    ushort4 h, l; unsigned short a, b;
    split2(v.x, a, b); h.x = a; l.x = b;
    split2(v.y, a, b); h.y = a; l.y = b;
    split2(v.z, a, b); h.z = a; l.z = b;
    split2(v.w, a, b); h.w = a; l.w = b;
    unsigned short* dst = out + r * 2 * K + k4 * 4;
    *(ushort4*)dst = h;
    *(ushort4*)(dst + K) = l;
  }
}

__global__ __launch_bounds__(256) void transpose_cvt_split(const float* __restrict__ in,
    unsigned short* __restrict__ out, int R, int C)
{
  __shared__ float tile[32][33];
  in  += (size_t)blockIdx.z * R * C;
  out += (size_t)blockIdx.z * 2 * R * C;
  const int r0 = blockIdx.y * 32, c0 = blockIdx.x * 32;
  const int tr = threadIdx.x >> 5, tc = threadIdx.x & 31;
#pragma unroll
  for (int i = 0; i < 4; ++i)
    tile[tr + i * 8][tc] = in[(size_t)(r0 + tr + i * 8) * C + c0 + tc];
  __syncthreads();
#pragma unroll
  for (int i = 0; i < 4; ++i) {
    unsigned short h, l;
    split2(tile[tc][tr + i * 8], h, l);
    const size_t o = (size_t)(c0 + tr + i * 8) * 2 * R + r0 + tc;
    out[o] = h;
    out[o + R] = l;
  }
}

__global__ __launch_bounds__(256) void transpose_cvt(const float* __restrict__ in,
    unsigned short* __restrict__ out, int R, int C)
{
  __shared__ float tile[32][33];
  const int r0 = blockIdx.y * 32, c0 = blockIdx.x * 32;
  const int tr = threadIdx.x >> 5, tc = threadIdx.x & 31;
#pragma unroll
  for (int i = 0; i < 4; ++i)
    tile[tr + i * 8][tc] = in[(size_t)(r0 + tr + i * 8) * C + c0 + tc];
  __syncthreads();
#pragma unroll
  for (int i = 0; i < 4; ++i)
    out[(size_t)(c0 + tr + i * 8) * R + r0 + tc] = f2bf(tile[tc][tr + i * 8]);
}

// ---------------- embedding + positional ----------------

__global__ __launch_bounds__(256) void embed_kernel(const int* __restrict__ ids,
    const float* __restrict__ Wv, float* __restrict__ x)
{
  const int t = blockIdx.x;
  const int id = ids[t];
  const int l = t & (SEQ - 1);
  const float pos = (float)l;
  const int d0 = threadIdx.x * 4;
  const float i0 = (float)(d0 >> 1);
  const float f0 = expf(-0.017988946039016f * i0);
  const float f1 = expf(-0.017988946039016f * (i0 + 1.f));
  const float a0 = pos * f0, a1 = pos * f1;
  float4 v;
  v.x = Wv[(size_t)(d0 + 0) * VOCAB + id] + sinf(a0);
  v.y = Wv[(size_t)(d0 + 1) * VOCAB + id] + cosf(a0);
  v.z = Wv[(size_t)(d0 + 2) * VOCAB + id] + sinf(a1);
  v.w = Wv[(size_t)(d0 + 3) * VOCAB + id] + cosf(a1);
  ((float4*)(x + (size_t)t * 1024))[threadIdx.x] = v;
}

// ---------------- layernorm (f32 in -> hi/lo bf16 planes out, stride 2048) ----------------

__global__ __launch_bounds__(256) void layernorm_split(const float* __restrict__ x,
    const float* __restrict__ g, const float* __restrict__ be,
    unsigned short* __restrict__ out)
{
  const int row = blockIdx.x;
  const float4 v = ((const float4*)(x + (size_t)row * 1024))[threadIdx.x];
  float s = v.x + v.y + v.z + v.w;
  float q = v.x * v.x + v.y * v.y + v.z * v.z + v.w * v.w;
#pragma unroll
  for (int o = 32; o; o >>= 1) { s += __shfl_xor(s, o); q += __shfl_xor(q, o); }
  __shared__ float ss[4], qq[4];
  const int w = threadIdx.x >> 6;
  if ((threadIdx.x & 63) == 0) { ss[w] = s; qq[w] = q; }
  __syncthreads();
  s = ss[0] + ss[1] + ss[2] + ss[3];
  q = qq[0] + qq[1] + qq[2] + qq[3];
  const float mean = s * (1.f / 1024.f);
  const float var = q * (1.f / 1024.f) - mean * mean;
  const float rstd = rsqrtf(var + 1e-5f);
  const float4 gv = ((const float4*)g)[threadIdx.x];
  const float4 bv = ((const float4*)be)[threadIdx.x];
  float4 y;
  y.x = (v.x - mean) * rstd * gv.x + bv.x;
  y.y = (v.y - mean) * rstd * gv.y + bv.y;
  y.z = (v.z - mean) * rstd * gv.z + bv.z;
  y.w = (v.w - mean) * rstd * gv.w + bv.w;
  ushort4 h4, l4; unsigned short a, b;
  split2(y.x, a, b); h4.x = a; l4.x = b;
  split2(y.y, a, b); h4.y = a; l4.y = b;
  split2(y.z, a, b); h4.z = a; l4.z = b;
  split2(y.w, a, b); h4.w = a; l4.w = b;
  unsigned short* dst = out + (size_t)row * 2048 + threadIdx.x * 4;
  *(ushort4*)dst = h4;
  *(ushort4*)(dst + 1024) = l4;
}

// ---------------- split GEMM: C[M,N] = A[M,K] * B[N,K]^T, near-f32 precision ----------------
// global_load_lds width-16 staging + XOR slot-swizzle. SWAPG=1: brow on fast axis
// (devocab: consecutive blocks share B-panel -> L2 reuse).

template<int EPI, int SPLIT, int SWAPG>
__global__ __launch_bounds__(256) void gemm_bt(
    const unsigned short* __restrict__ A, const unsigned short* __restrict__ B,
    float* __restrict__ Cf, unsigned short* __restrict__ Cb,
    const float* __restrict__ bias, const float* __restrict__ res,
    int M, int N, int K)
{
  __shared__ __align__(16) unsigned short As[128 * 64];
  __shared__ __align__(16) unsigned short Bs[128 * 64];
  const int tid = threadIdx.x;
  const int lane = tid & 63, w = tid >> 6;
  const int wr = w >> 1, wc = w & 1;
  const int bxi = SWAPG ? blockIdx.y : blockIdx.x;
  const int byi = SWAPG ? blockIdx.x : blockIdx.y;
  const int brow = byi * 128, bcol = bxi * 128;

  const int SA = 2 * K;                         // A always hi/lo
  const int SB = (SPLIT == 3) ? 2 * K : K;
  const int KEFF = SPLIT * K;
  fx4 acc[4][4];
  const fx4 zero = {0.f, 0.f, 0.f, 0.f};
#pragma unroll
  for (int i = 0; i < 4; ++i)
#pragma unroll
    for (int j = 0; j < 4; ++j) acc[i][j] = zero;

  const unsigned short* Ab = A + (size_t)brow * SA;
  const unsigned short* Bb = B + (size_t)bcol * SB;

  for (int k0 = 0; k0 < KEFF; k0 += 64) {
    int ka, kb;
    if (SPLIT == 3) {
      ka = (k0 < 2 * K) ? k0 : k0 - 2 * K;      // hi | lo | hi
      kb = (k0 < K) ? k0 : k0 - K;              // hi | hi | lo
    } else {
      ka = k0;                                  // hi | lo
      kb = (k0 < K) ? k0 : k0 - K;              // hi | hi
    }
    const unsigned short* Aseg = Ab + ka;
    const unsigned short* Bseg = Bb + kb;
#pragma unroll
    for (int it = 0; it < 4; ++it) {
      const int idx = it * 256 + tid;          // 0..1023
      const int r = idx >> 3;                  // tile row 0..127
      const int c = ((idx & 7) ^ (r & 7)) * 8; // pre-swizzled source slot
      GLL16(&Aseg[(size_t)r * SA + c], &As[idx * 8]);
      GLL16(&Bseg[(size_t)r * SB + c], &Bs[idx * 8]);
    }
    __syncthreads();
#pragma unroll
    for (int kk = 0; kk < 2; ++kk) {
      short8 af[4], bfv[4];
      const int slot = ((kk * 4 + (lane >> 4)) ^ (lane & 7)) * 8;
#pragma unroll
      for (int f = 0; f < 4; ++f)
        af[f] = *(const short8*)&As[(wr * 64 + f * 16 + (lane & 15)) * 64 + slot];
#pragma unroll
      for (int f = 0; f < 4; ++f)
        bfv[f] = *(const short8*)&Bs[(wc * 64 + f * 16 + (lane & 15)) * 64 + slot];
#pragma unroll
      for (int i = 0; i < 4; ++i)
#pragma unroll
        for (int j = 0; j < 4; ++j)
          acc[i][j] = __builtin_amdgcn_mfma_f32_16x16x32_bf16(af[i], bfv[j], acc[i][j], 0, 0, 0);
    }
    __syncthreads();
  }

  // C/D layout: col = lane&15, row = (lane>>4)*4 + reg
  const int r0 = brow + wr * 64 + (lane >> 4) * 4;
  const int c0 = bcol + wc * 64 + (lane & 15);
#pragma unroll
  for (int i = 0; i < 4; ++i) {
#pragma unroll
    for (int j = 0; j < 4; ++j) {
      const int cc = c0 + j * 16;
#pragma unroll
      for (int qi = 0; qi < 4; ++qi) {
        const int rr = r0 + i * 16 + qi;
        const size_t off = (size_t)rr * N + cc;
        const float val = acc[i][j][qi];
        if (EPI == 0) {
          Cf[off] = val;
        } else if (EPI == 2) {
          Cf[off] = res[off] + val;
        } else if (EPI == 3) {
          unsigned short hh, ll;
          split2(gelu_exact(val + bias[cc]), hh, ll);
          Cb[(size_t)rr * (2 * N) + cc] = hh;
          Cb[(size_t)rr * (2 * N) + N + cc] = ll;
        } else {
          Cf[off] = res[off] + val + bias[cc];
        }
      }
    }
  }
}

// ---------------- attention v6: MFMA flash, fixed-base softmax ----------------
// Block = (b, h, qt): 64 q-rows; 4 waves x 16 rows. grid = B*H*8 = 1024, heavy qt first.
// Per 64-key chunk:
//   stage Kh/Kl (bf16 split) + Vt (V^T bf16-hi), XOR-slot-swizzled;
//   QK^T: S = Qh*Kh + Ql*Kh + Qh*Kl (MFMA, f32 acc)  [scores ~f32-exact]
//   p = exp(30*tanh(s/8))  (bounded -> fixed base, no max/rescale; row-sums in regs)
//   P -> bf16 hi/lo via wave-private LDS (C-layout -> A-frag layout)
//   PV: O += Ph*Vt + Pl*Vt (MFMA)
// End: 4-shuffle row-sum reduce, O = acc/sum, write hi/lo planes.

__global__ __launch_bounds__(256, 4) void attn_kernel(
    const float* __restrict__ qkvf,
    const int* __restrict__ amask,
    unsigned short* __restrict__ out2)
{
  const int bid = blockIdx.x;
  const int qt = 7 - (bid & 7);            // heavy causal tiles dispatch first
  const int h  = (bid >> 3) & 15;
  const int b  = bid >> 7;

  __shared__ __align__(16) unsigned short Kh[64 * 64];
  __shared__ __align__(16) unsigned short Kl[64 * 64];
  __shared__ __align__(16) unsigned short Vt[64 * 64];      // [d][key] hi
  __shared__ __align__(16) unsigned short Ph[4][16 * 64];   // wave-private [row][key]
  __shared__ __align__(16) unsigned short Pl[4][16 * 64];

  const int tid = threadIdx.x, lane = tid & 63, w = tid >> 6;
  const size_t base = (size_t)b * SEQ;
  const int qrow0 = qt * 64 + w * 16;

  // Q fragments in regs: row = lane&15 (of wave tile), k = (lane>>4)*8+e, 2 k-steps
  short8 qh[2], ql[2];
  {
    const int row = qrow0 + (lane & 15);
    const float* qp = &qkvf[(base + row) * 3072 + h * 64 + (lane >> 4) * 8];
#pragma unroll
    for (int ks = 0; ks < 2; ++ks) {
      const float4 a = *(const float4*)(qp + ks * 32);
      const float4 c = *(const float4*)(qp + ks * 32 + 4);
      short8 hh, ll; unsigned short th, tl;
      split2(a.x, th, tl); hh[0] = (short)th; ll[0] = (short)tl;
      split2(a.y, th, tl); hh[1] = (short)th; ll[1] = (short)tl;
      split2(a.z, th, tl); hh[2] = (short)th; ll[2] = (short)tl;
      split2(a.w, th, tl); hh[3] = (short)th; ll[3] = (short)tl;
      split2(c.x, th, tl); hh[4] = (short)th; ll[4] = (short)tl;
      split2(c.y, th, tl); hh[5] = (short)th; ll[5] = (short)tl;
      split2(c.z, th, tl); hh[6] = (short)th; ll[6] = (short)tl;
      split2(c.w, th, tl); hh[7] = (short)th; ll[7] = (short)tl;
      qh[ks] = hh; ql[ks] = ll;
    }
  }

  fx4 oacc[4];
  float sumr[4] = {0.f, 0.f, 0.f, 0.f};
#pragma unroll
  for (int j = 0; j < 4; ++j) oacc[j] = (fx4){0.f, 0.f, 0.f, 0.f};

  for (int kc = 0; kc <= qt; ++kc) {
    const int c0 = kc * 64;
    __syncthreads();                        // prev chunk fully consumed
#pragma unroll
    for (int it = 0; it < 4; ++it) {        // stage K hi/lo + V^T (coalesced reads)
      const int idx = it * 256 + tid;       // 1024 = 64 keys x 16 c4
      const int key = idx >> 4, c4 = idx & 15;
      const float4 kv = *(const float4*)&qkvf[(base + c0 + key) * 3072 + 1024 + h * 64 + c4 * 4];
      ushort4 kh4, kl4;
      split2(kv.x, kh4.x, kl4.x); split2(kv.y, kh4.y, kl4.y);
      split2(kv.z, kh4.z, kl4.z); split2(kv.w, kh4.w, kl4.w);
      const int sl = (((c4 >> 1) ^ (key & 7)) * 8 + (c4 & 1) * 4);
      *(ushort4*)&Kh[key * 64 + sl] = kh4;
      *(ushort4*)&Kl[key * 64 + sl] = kl4;
      const float4 vv = *(const float4*)&qkvf[(base + c0 + key) * 3072 + 2048 + h * 64 + c4 * 4];
      {
        const int d0 = c4 * 4;
        Vt[(d0 + 0) * 64 + ((key >> 3) ^ ((d0 + 0) & 7)) * 8 + (key & 7)] = f2bf(vv.x);
        Vt[(d0 + 1) * 64 + ((key >> 3) ^ ((d0 + 1) & 7)) * 8 + (key & 7)] = f2bf(vv.y);
        Vt[(d0 + 2) * 64 + ((key >> 3) ^ ((d0 + 2) & 7)) * 8 + (key & 7)] = f2bf(vv.z);
        Vt[(d0 + 3) * 64 + ((key >> 3) ^ ((d0 + 3) & 7)) * 8 + (key & 7)] = f2bf(vv.w);
      }
    }
    __syncthreads();

    const bool diag = (kc == qt);
    // QK^T per 16-key tile -> p -> P planes (wave-private)
#pragma unroll
    for (int j = 0; j < 4; ++j) {
      fx4 sacc = {0.f, 0.f, 0.f, 0.f};
#pragma unroll
      for (int ks = 0; ks < 2; ++ks) {
        const int krow = j * 16 + (lane & 15);
        const int soff = ((ks * 4 + (lane >> 4)) ^ (krow & 7)) * 8;
        const short8 bh = *(const short8*)&Kh[krow * 64 + soff];
        const short8 bl = *(const short8*)&Kl[krow * 64 + soff];
        sacc = __builtin_amdgcn_mfma_f32_16x16x32_bf16(qh[ks], bh, sacc, 0, 0, 0);
        sacc = __builtin_amdgcn_mfma_f32_16x16x32_bf16(ql[ks], bh, sacc, 0, 0, 0);
        sacc = __builtin_amdgcn_mfma_f32_16x16x32_bf16(qh[ks], bl, sacc, 0, 0, 0);
      }
      const int key = c0 + j * 16 + (lane & 15);
      const int am = amask[b * SEQ + key];
      const int col = j * 16 + (lane & 15);
#pragma unroll
      for (int qi = 0; qi < 4; ++qi) {
        const int prow = (lane >> 4) * 4 + qi;
        const int row = qrow0 + prow;
        const float e = __expf(sacc[qi] * 0.25f);
        const float S = 30.f - 60.f / (e + 1.f);   // 30*tanh(s/8), NaN-safe
        float p = __expf(S);
        const bool valid = (!diag || (key <= row)) && (am != 0);
        p = valid ? p : 0.f;
        sumr[qi] += p;
        unsigned short ph_, pl_;
        split2(p, ph_, pl_);
        const int ss = (((col >> 3) ^ (prow & 7)) * 8) + (col & 7);
        Ph[w][prow * 64 + ss] = ph_;
        Pl[w][prow * 64 + ss] = pl_;
      }
    }

    // PV: A = P frags (row = lane&15), B = Vt frags (row = d)
#pragma unroll
    for (int jd = 0; jd < 4; ++jd) {
#pragma unroll
      for (int ks = 0; ks < 2; ++ks) {
        const int drow = jd * 16 + (lane & 15);
        const int soff = ((ks * 4 + (lane >> 4)) ^ (drow & 7)) * 8;
        const short8 bv = *(const short8*)&Vt[drow * 64 + soff];
        const int psoff = ((ks * 4 + (lane >> 4)) ^ (lane & 7)) * 8;
        const short8 pa = *(const short8*)&Ph[w][(lane & 15) * 64 + psoff];
        const short8 pb = *(const short8*)&Pl[w][(lane & 15) * 64 + psoff];
        oacc[jd] = __builtin_amdgcn_mfma_f32_16x16x32_bf16(pa, bv, oacc[jd], 0, 0, 0);
        oacc[jd] = __builtin_amdgcn_mfma_f32_16x16x32_bf16(pb, bv, oacc[jd], 0, 0, 0);
      }
    }
  }

  // row-sum reduce over the 16-lane col group, then normalize + write
#pragma unroll
  for (int qi = 0; qi < 4; ++qi) {
    float cs = sumr[qi];
#pragma unroll
    for (int o = 1; o <= 8; o <<= 1) cs += __shfl_xor(cs, o);
    sumr[qi] = cs;
  }
#pragma unroll
  for (int jd = 0; jd < 4; ++jd) {
#pragma unroll
    for (int qi = 0; qi < 4; ++qi) {
      const int row = qrow0 + (lane >> 4) * 4 + qi;
      const int d = jd * 16 + (lane & 15);
      const float o = oacc[jd][qi] / sumr[qi];
      unsigned short hh, ll;
      split2(o, hh, ll);
      out2[(base + row) * 2048 + h * 64 + d] = hh;
      out2[(base + row) * 2048 + 1024 + h * 64 + d] = ll;
    }
  }
}

extern "C" void kernel_launch(void* const* d_in, const int* in_sizes, int n_in,
                              void* d_out, int out_size, void* d_ws, size_t ws_size,
                              hipStream_t stream) {
  const int*   ids       = (const int*)d_in[0];
  const int*   amask     = (const int*)d_in[1];
  const float* W_vocab   = (const float*)d_in[2];
  const float* W_devocab = (const float*)d_in[3];
  const float* WQ        = (const float*)d_in[4];
  const float* WK        = (const float*)d_in[5];
  const float* WV        = (const float*)d_in[6];
  const float* W_O       = (const float*)d_in[7];
  const float* gamma1    = (const float*)d_in[8];
  const float* beta1     = (const float*)d_in[9];
  const float* gamma2    = (const float*)d_in[10];
  const float* beta2     = (const float*)d_in[11];
  const float* W_up      = (const float*)d_in[12];
  const float* b_up      = (const float*)d_in[13];
  const float* W_down    = (const float*)d_in[14];
  const float* b_down    = (const float*)d_in[15];
  const float* gamma_f   = (const float*)d_in[16];
  const float* beta_f    = (const float*)d_in[17];

  char* p = (char*)d_ws;
  auto alloc = [&](size_t bytes) { char* r = p; p += (bytes + 255) & ~(size_t)255; return r; };

  unsigned short* WQKV2 = (unsigned short*)alloc((size_t)NLAYERS * 3072 * 2048 * 2);
  unsigned short* WO2   = (unsigned short*)alloc((size_t)NLAYERS * 1024 * 2048 * 2);
  unsigned short* WUp2  = (unsigned short*)alloc((size_t)NLAYERS * 4096 * 2048 * 2);
  unsigned short* WDn2  = (unsigned short*)alloc((size_t)NLAYERS * 1024 * 8192 * 2);
  unsigned short* WDev1 = (unsigned short*)alloc((size_t)VOCAB * 1024 * 2);
  float* x    = (float*)alloc((size_t)NTOK * 1024 * 4);
  float* z1   = (float*)alloc((size_t)NTOK * 1024 * 4);
  unsigned short* u2    = (unsigned short*)alloc((size_t)NTOK * 2048 * 2);   // also v1 / xf
  float* qkvf = (float*)alloc((size_t)NTOK * 3072 * 4);
  unsigned short* attn2 = (unsigned short*)alloc((size_t)NTOK * 2048 * 2);
  unsigned short* h2    = (unsigned short*)alloc((size_t)NTOK * 8192 * 2);
  (void)ws_size; (void)in_sizes; (void)n_in; (void)out_size;

  // ---- weight prep (hi/lo split planes) ----
  cvt_qkv_split<<<2048, 256, 0, stream>>>(WQ, WK, WV, WQKV2);
  cvt_split<<<2048, 256, 0, stream>>>(W_O, WO2, (long)NLAYERS * 1024, 1024);
  transpose_cvt_split<<<dim3(4096 / 32, 1024 / 32, NLAYERS), 256, 0, stream>>>(W_up, WUp2, 1024, 4096);
  transpose_cvt_split<<<dim3(1024 / 32, 4096 / 32, NLAYERS), 256, 0, stream>>>(W_down, WDn2, 4096, 1024);
  transpose_cvt<<<dim3(VOCAB / 32, 1024 / 32, 1), 256, 0, stream>>>(W_devocab, WDev1, 1024, VOCAB);

  // ---- embedding ----
  embed_kernel<<<NTOK, 256, 0, stream>>>(ids, W_vocab, x);

  // ---- layers ----
  for (int l = 0; l < NLAYERS; ++l) {
    layernorm_split<<<NTOK, 256, 0, stream>>>(x, gamma1 + l * 1024, beta1 + l * 1024, u2);
    // fused QKV (split-3, f32 out): [4096,3072]
    gemm_bt<0, 3, 0><<<dim3(3072 / 128, NTOK / 128), 256, 0, stream>>>(
        u2, WQKV2 + (size_t)l * 3072 * 2048, qkvf, nullptr, nullptr, nullptr,
        NTOK, 3072, 1024);
    attn_kernel<<<BATCH * NHEADS * 8, 256, 0, stream>>>(qkvf, amask, attn2);
    // z1 = x + attn @ W_O^T
    gemm_bt<2, 3, 0><<<dim3(1024 / 128, NTOK / 128), 256, 0, stream>>>(
        attn2, WO2 + (size_t)l * 1024 * 2048, z1, nullptr, nullptr, x,
        NTOK, 1024, 1024);
    layernorm_split<<<NTOK, 256, 0, stream>>>(z1, gamma2 + l * 1024, beta2 + l * 1024, u2);
    // h = gelu(v1 @ W_up + b_up), hi/lo out
    gemm_bt<3, 3, 0><<<dim3(4096 / 128, NTOK / 128), 256, 0, stream>>>(
        u2, WUp2 + (size_t)l * 4096 * 2048, nullptr, h2, b_up + l * 4096, nullptr,
        NTOK, 4096, 1024);
    // x = z1 + h @ W_down + b_down
    gemm_bt<4, 3, 0><<<dim3(1024 / 128, NTOK / 128), 256, 0, stream>>>(
        h2, WDn2 + (size_t)l * 1024 * 8192, x, nullptr, b_down + l * 1024, z1,
        NTOK, 1024, 4096);
  }

  // ---- final LN + devocab (split-2; brow-major grid for B reuse) ----
  layernorm_split<<<NTOK, 256, 0, stream>>>(x, gamma_f, beta_f, u2);
  gemm_bt<0, 2, 1><<<dim3(NTOK / 128, VOCAB / 128), 256, 0, stream>>>(
      u2, WDev1, (float*)d_out, nullptr, nullptr, nullptr,
      NTOK, VOCAB, 1024);
}

// Round 14
// 8806.467 us; speedup vs baseline: 4.5114x; 1.0629x over previous
//
#include <hip/hip_runtime.h>
#include <math.h>

#define D_MODEL 1024
#define NHEADS 16
#define DHEAD 64
#define NLAYERS 12
#define VOCAB 32000
#define BATCH 8
#define SEQ 512
#define NTOK (BATCH*SEQ)   // 4096

using short8 = __attribute__((ext_vector_type(8))) short;
using fx4    = __attribute__((ext_vector_type(4))) float;
using fx16   = __attribute__((ext_vector_type(16))) float;

#define GLL16(g, l) __builtin_amdgcn_global_load_lds( \
    (const __attribute__((address_space(1))) unsigned int*)(g), \
    (__attribute__((address_space(3))) unsigned int*)(l), 16, 0, 0)

__device__ __forceinline__ unsigned short f2bf(float f) {
  union { float f; unsigned u; } v; v.f = f;
  unsigned r = v.u + 0x7FFFu + ((v.u >> 16) & 1u);
  return (unsigned short)(r >> 16);
}
__device__ __forceinline__ float bf2f(unsigned short u) {
  union { unsigned u; float f; } v; v.u = ((unsigned)u) << 16;
  return v.f;
}
__device__ __forceinline__ void split2(float x, unsigned short& h, unsigned short& l) {
  h = f2bf(x);
  l = f2bf(x - bf2f(h));
}
__device__ __forceinline__ float gelu_exact(float x) {
  return 0.5f * x * (1.f + erff(x * 0.70710678118654752f));
}

// ---------------- weight conversion (hi/lo split planes) ----------------

__global__ __launch_bounds__(256) void cvt_qkv_split(const float* __restrict__ WQ,
    const float* __restrict__ WK, const float* __restrict__ WV,
    unsigned short* __restrict__ out)
{
  const long total = 12L * 3072 * 256;     // float4 units
  const long stride = (long)gridDim.x * blockDim.x;
  for (long t = (long)blockIdx.x * blockDim.x + threadIdx.x; t < total; t += stride) {
    const long layer = t / (3072L * 256);
    const long rem = t - layer * (3072L * 256);
    const int n = (int)(rem >> 8);
    const int k4 = (int)(rem & 255);
    const float* src;
    if (n < 1024)       src = WQ + ((size_t)layer * 1024 + n) * 1024;
    else if (n < 2048)  src = WK + ((size_t)layer * 1024 + (n - 1024)) * 1024;
    else                src = WV + ((size_t)layer * 1024 + (n - 2048)) * 1024;
    const float4 v = *(const float4*)(src + k4 * 4);
    ushort4 h, l; unsigned short a, b;
    split2(v.x, a, b); h.x = a; l.x = b;
    split2(v.y, a, b); h.y = a; l.y = b;
    split2(v.z, a, b); h.z = a; l.z = b;
    split2(v.w, a, b); h.w = a; l.w = b;
    unsigned short* dst = out + ((size_t)layer * 3072 + n) * 2048 + k4 * 4;
    *(ushort4*)dst = h;
    *(ushort4*)(dst + 1024) = l;
  }
}

__global__ __launch_bounds__(256) void cvt_split(const float* __restrict__ in,
    unsigned short* __restrict__ out, long rows, int K)
{
  const int K4 = K >> 2;
  const long total = rows * K4;
  const long stride = (long)gridDim.x * blockDim.x;
  for (long t = (long)blockIdx.x * blockDim.x + threadIdx.x; t < total; t += stride) {
    const long r = t / K4;
    const int k4 = (int)(t - r * K4);
    const float4 v = *(const float4*)(in + r * K + k4 * 4);
    ushort4 h, l; unsigned short a, b;
    split2(v.x, a, b); h.x = a; l.x = b;
    split2(v.y, a, b); h.y = a; l.y = b;
    split2(v.z, a, b); h.z = a; l.z = b;
    split2(v.w, a, b); h.w = a; l.w = b;
    unsigned short* dst = out + r * 2 * K + k4 * 4;
    *(ushort4*)dst = h;
    *(ushort4*)(dst + K) = l;
  }
}

__global__ __launch_bounds__(256) void transpose_cvt_split(const float* __restrict__ in,
    unsigned short* __restrict__ out, int R, int C)
{
  __shared__ float tile[32][33];
  in  += (size_t)blockIdx.z * R * C;
  out += (size_t)blockIdx.z * 2 * R * C;
  const int r0 = blockIdx.y * 32, c0 = blockIdx.x * 32;
  const int tr = threadIdx.x >> 5, tc = threadIdx.x & 31;
#pragma unroll
  for (int i = 0; i < 4; ++i)
    tile[tr + i * 8][tc] = in[(size_t)(r0 + tr + i * 8) * C + c0 + tc];
  __syncthreads();
#pragma unroll
  for (int i = 0; i < 4; ++i) {
    unsigned short h, l;
    split2(tile[tc][tr + i * 8], h, l);
    const size_t o = (size_t)(c0 + tr + i * 8) * 2 * R + r0 + tc;
    out[o] = h;
    out[o + R] = l;
  }
}

__global__ __launch_bounds__(256) void transpose_cvt(const float* __restrict__ in,
    unsigned short* __restrict__ out, int R, int C)
{
  __shared__ float tile[32][33];
  const int r0 = blockIdx.y * 32, c0 = blockIdx.x * 32;
  const int tr = threadIdx.x >> 5, tc = threadIdx.x & 31;
#pragma unroll
  for (int i = 0; i < 4; ++i)
    tile[tr + i * 8][tc] = in[(size_t)(r0 + tr + i * 8) * C + c0 + tc];
  __syncthreads();
#pragma unroll
  for (int i = 0; i < 4; ++i)
    out[(size_t)(c0 + tr + i * 8) * R + r0 + tc] = f2bf(tile[tc][tr + i * 8]);
}

// ---------------- embedding + positional ----------------

__global__ __launch_bounds__(256) void embed_kernel(const int* __restrict__ ids,
    const float* __restrict__ Wv, float* __restrict__ x)
{
  const int t = blockIdx.x;
  const int id = ids[t];
  const int l = t & (SEQ - 1);
  const float pos = (float)l;
  const int d0 = threadIdx.x * 4;
  const float i0 = (float)(d0 >> 1);
  const float f0 = expf(-0.017988946039016f * i0);
  const float f1 = expf(-0.017988946039016f * (i0 + 1.f));
  const float a0 = pos * f0, a1 = pos * f1;
  float4 v;
  v.x = Wv[(size_t)(d0 + 0) * VOCAB + id] + sinf(a0);
  v.y = Wv[(size_t)(d0 + 1) * VOCAB + id] + cosf(a0);
  v.z = Wv[(size_t)(d0 + 2) * VOCAB + id] + sinf(a1);
  v.w = Wv[(size_t)(d0 + 3) * VOCAB + id] + cosf(a1);
  ((float4*)(x + (size_t)t * 1024))[threadIdx.x] = v;
}

// ---------------- layernorm (f32 in -> hi/lo bf16 planes out, stride 2048) ----------------

__global__ __launch_bounds__(256) void layernorm_split(const float* __restrict__ x,
    const float* __restrict__ g, const float* __restrict__ be,
    unsigned short* __restrict__ out)
{
  const int row = blockIdx.x;
  const float4 v = ((const float4*)(x + (size_t)row * 1024))[threadIdx.x];
  float s = v.x + v.y + v.z + v.w;
  float q = v.x * v.x + v.y * v.y + v.z * v.z + v.w * v.w;
#pragma unroll
  for (int o = 32; o; o >>= 1) { s += __shfl_xor(s, o); q += __shfl_xor(q, o); }
  __shared__ float ss[4], qq[4];
  const int w = threadIdx.x >> 6;
  if ((threadIdx.x & 63) == 0) { ss[w] = s; qq[w] = q; }
  __syncthreads();
  s = ss[0] + ss[1] + ss[2] + ss[3];
  q = qq[0] + qq[1] + qq[2] + qq[3];
  const float mean = s * (1.f / 1024.f);
  const float var = q * (1.f / 1024.f) - mean * mean;
  const float rstd = rsqrtf(var + 1e-5f);
  const float4 gv = ((const float4*)g)[threadIdx.x];
  const float4 bv = ((const float4*)be)[threadIdx.x];
  float4 y;
  y.x = (v.x - mean) * rstd * gv.x + bv.x;
  y.y = (v.y - mean) * rstd * gv.y + bv.y;
  y.z = (v.z - mean) * rstd * gv.z + bv.z;
  y.w = (v.w - mean) * rstd * gv.w + bv.w;
  ushort4 h4, l4; unsigned short a, b;
  split2(y.x, a, b); h4.x = a; l4.x = b;
  split2(y.y, a, b); h4.y = a; l4.y = b;
  split2(y.z, a, b); h4.z = a; l4.z = b;
  split2(y.w, a, b); h4.w = a; l4.w = b;
  unsigned short* dst = out + (size_t)row * 2048 + threadIdx.x * 4;
  *(ushort4*)dst = h4;
  *(ushort4*)(dst + 1024) = l4;
}

// ---------------- split GEMM: C[M,N] = A[M,K] * B[N,K]^T, near-f32 precision ----------------
// 32x32x16 MFMA (half the instructions vs 16x16x32, ~20% faster matrix pipe).
// global_load_lds width-16 staging + XOR slot-swizzle (linear LDS dest, pre-swizzled
// global source, swizzled read). SWAPG=1: brow on fast axis (devocab B-panel L2 reuse).
// A/B frag: row = lane&31, k = (lane>>5)*8 + e.
// C/D frag: col = lane&31, row = (reg&3) + 8*(reg>>2) + 4*(lane>>5)  [m74/m101].

template<int EPI, int SPLIT, int SWAPG>
__global__ __launch_bounds__(256) void gemm_bt(
    const unsigned short* __restrict__ A, const unsigned short* __restrict__ B,
    float* __restrict__ Cf, unsigned short* __restrict__ Cb,
    const float* __restrict__ bias, const float* __restrict__ res,
    int M, int N, int K)
{
  __shared__ __align__(16) unsigned short As[128 * 64];
  __shared__ __align__(16) unsigned short Bs[128 * 64];
  const int tid = threadIdx.x;
  const int lane = tid & 63, w = tid >> 6;
  const int wr = w >> 1, wc = w & 1;
  const int bxi = SWAPG ? blockIdx.y : blockIdx.x;
  const int byi = SWAPG ? blockIdx.x : blockIdx.y;
  const int brow = byi * 128, bcol = bxi * 128;

  const int SA = 2 * K;                         // A always hi/lo
  const int SB = (SPLIT == 3) ? 2 * K : K;
  const int KEFF = SPLIT * K;
  fx16 acc[2][2];
#pragma unroll
  for (int i = 0; i < 2; ++i)
#pragma unroll
    for (int j = 0; j < 2; ++j)
#pragma unroll
      for (int e = 0; e < 16; ++e) acc[i][j][e] = 0.f;

  const unsigned short* Ab = A + (size_t)brow * SA;
  const unsigned short* Bb = B + (size_t)bcol * SB;

  for (int k0 = 0; k0 < KEFF; k0 += 64) {
    int ka, kb;
    if (SPLIT == 3) {
      ka = (k0 < 2 * K) ? k0 : k0 - 2 * K;      // hi | lo | hi
      kb = (k0 < K) ? k0 : k0 - K;              // hi | hi | lo
    } else {
      ka = k0;                                  // hi | lo
      kb = (k0 < K) ? k0 : k0 - K;              // hi | hi
    }
    const unsigned short* Aseg = Ab + ka;
    const unsigned short* Bseg = Bb + kb;
#pragma unroll
    for (int it = 0; it < 4; ++it) {
      const int idx = it * 256 + tid;          // 0..1023
      const int r = idx >> 3;                  // tile row 0..127
      const int c = ((idx & 7) ^ (r & 7)) * 8; // pre-swizzled source slot
      GLL16(&Aseg[(size_t)r * SA + c], &As[idx * 8]);
      GLL16(&Bseg[(size_t)r * SB + c], &Bs[idx * 8]);
    }
    __syncthreads();   // drains vmcnt (global_load_lds) before ds_read
#pragma unroll
    for (int ks = 0; ks < 4; ++ks) {           // K = 4 x 16
      const int slot = ((ks * 2 + (lane >> 5)) ^ (lane & 7)) * 8;
      short8 af[2], bfv[2];
#pragma unroll
      for (int ti = 0; ti < 2; ++ti)
        af[ti] = *(const short8*)&As[(wr * 64 + ti * 32 + (lane & 31)) * 64 + slot];
#pragma unroll
      for (int tj = 0; tj < 2; ++tj)
        bfv[tj] = *(const short8*)&Bs[(wc * 64 + tj * 32 + (lane & 31)) * 64 + slot];
#pragma unroll
      for (int ti = 0; ti < 2; ++ti)
#pragma unroll
        for (int tj = 0; tj < 2; ++tj)
          acc[ti][tj] = __builtin_amdgcn_mfma_f32_32x32x16_bf16(af[ti], bfv[tj], acc[ti][tj], 0, 0, 0);
    }
    __syncthreads();
  }

  // C/D: col = lane&31, row = (reg&3) + 8*(reg>>2) + 4*(lane>>5)
  const int cl = lane & 31;
  const int rb = 4 * (lane >> 5);
#pragma unroll
  for (int ti = 0; ti < 2; ++ti) {
#pragma unroll
    for (int tj = 0; tj < 2; ++tj) {
      const int cc = bcol + wc * 64 + tj * 32 + cl;
#pragma unroll
      for (int reg = 0; reg < 16; ++reg) {
        const int rr = brow + wr * 64 + ti * 32 + (reg & 3) + 8 * (reg >> 2) + rb;
        const size_t off = (size_t)rr * N + cc;
        const float val = acc[ti][tj][reg];
        if (EPI == 0) {
          Cf[off] = val;
        } else if (EPI == 2) {
          Cf[off] = res[off] + val;
        } else if (EPI == 3) {
          unsigned short hh, ll;
          split2(gelu_exact(val + bias[cc]), hh, ll);
          Cb[(size_t)rr * (2 * N) + cc] = hh;
          Cb[(size_t)rr * (2 * N) + N + cc] = ll;
        } else {
          Cf[off] = res[off] + val + bias[cc];
        }
      }
    }
  }
}

// ---------------- attention v7: MFMA flash + V hi/lo (restore f32-V precision) ----------------
// As v6 but V staged as hi AND lo planes; PV = Ph*Vh + Pl*Vh + Ph*Vl (residual ~Pl*Vl).
// LDS 48KB -> 3 blocks/CU.

__global__ __launch_bounds__(256, 3) void attn_kernel(
    const float* __restrict__ qkvf,
    const int* __restrict__ amask,
    unsigned short* __restrict__ out2)
{
  const int bid = blockIdx.x;
  const int qt = 7 - (bid & 7);            // heavy causal tiles dispatch first
  const int h  = (bid >> 3) & 15;
  const int b  = bid >> 7;

  __shared__ __align__(16) unsigned short Kh[64 * 64];
  __shared__ __align__(16) unsigned short Kl[64 * 64];
  __shared__ __align__(16) unsigned short Vt[64 * 64];      // [d][key] hi
  __shared__ __align__(16) unsigned short Vl[64 * 64];      // [d][key] lo
  __shared__ __align__(16) unsigned short Ph[4][16 * 64];   // wave-private [row][key]
  __shared__ __align__(16) unsigned short Pl[4][16 * 64];

  const int tid = threadIdx.x, lane = tid & 63, w = tid >> 6;
  const size_t base = (size_t)b * SEQ;
  const int qrow0 = qt * 64 + w * 16;

  // Q fragments in regs: row = lane&15 (of wave tile), k = (lane>>4)*8+e, 2 k-steps
  short8 qh[2], ql[2];
  {
    const int row = qrow0 + (lane & 15);
    const float* qp = &qkvf[(base + row) * 3072 + h * 64 + (lane >> 4) * 8];
#pragma unroll
    for (int ks = 0; ks < 2; ++ks) {
      const float4 a = *(const float4*)(qp + ks * 32);
      const float4 c = *(const float4*)(qp + ks * 32 + 4);
      short8 hh, ll; unsigned short th, tl;
      split2(a.x, th, tl); hh[0] = (short)th; ll[0] = (short)tl;
      split2(a.y, th, tl); hh[1] = (short)th; ll[1] = (short)tl;
      split2(a.z, th, tl); hh[2] = (short)th; ll[2] = (short)tl;
      split2(a.w, th, tl); hh[3] = (short)th; ll[3] = (short)tl;
      split2(c.x, th, tl); hh[4] = (short)th; ll[4] = (short)tl;
      split2(c.y, th, tl); hh[5] = (short)th; ll[5] = (short)tl;
      split2(c.z, th, tl); hh[6] = (short)th; ll[6] = (short)tl;
      split2(c.w, th, tl); hh[7] = (short)th; ll[7] = (short)tl;
      qh[ks] = hh; ql[ks] = ll;
    }
  }

  fx4 oacc[4];
  float sumr[4] = {0.f, 0.f, 0.f, 0.f};
#pragma unroll
  for (int j = 0; j < 4; ++j) oacc[j] = (fx4){0.f, 0.f, 0.f, 0.f};

  for (int kc = 0; kc <= qt; ++kc) {
    const int c0 = kc * 64;
    __syncthreads();                        // prev chunk fully consumed
#pragma unroll
    for (int it = 0; it < 4; ++it) {        // stage K hi/lo + V^T hi/lo (coalesced reads)
      const int idx = it * 256 + tid;       // 1024 = 64 keys x 16 c4
      const int key = idx >> 4, c4 = idx & 15;
      const float4 kv = *(const float4*)&qkvf[(base + c0 + key) * 3072 + 1024 + h * 64 + c4 * 4];
      ushort4 kh4, kl4;
      split2(kv.x, kh4.x, kl4.x); split2(kv.y, kh4.y, kl4.y);
      split2(kv.z, kh4.z, kl4.z); split2(kv.w, kh4.w, kl4.w);
      const int sl = (((c4 >> 1) ^ (key & 7)) * 8 + (c4 & 1) * 4);
      *(ushort4*)&Kh[key * 64 + sl] = kh4;
      *(ushort4*)&Kl[key * 64 + sl] = kl4;
      const float4 vv = *(const float4*)&qkvf[(base + c0 + key) * 3072 + 2048 + h * 64 + c4 * 4];
      {
        const int d0 = c4 * 4;
        unsigned short vh_, vl_;
        split2(vv.x, vh_, vl_);
        { const int o = (d0 + 0) * 64 + ((key >> 3) ^ ((d0 + 0) & 7)) * 8 + (key & 7); Vt[o] = vh_; Vl[o] = vl_; }
        split2(vv.y, vh_, vl_);
        { const int o = (d0 + 1) * 64 + ((key >> 3) ^ ((d0 + 1) & 7)) * 8 + (key & 7); Vt[o] = vh_; Vl[o] = vl_; }
        split2(vv.z, vh_, vl_);
        { const int o = (d0 + 2) * 64 + ((key >> 3) ^ ((d0 + 2) & 7)) * 8 + (key & 7); Vt[o] = vh_; Vl[o] = vl_; }
        split2(vv.w, vh_, vl_);
        { const int o = (d0 + 3) * 64 + ((key >> 3) ^ ((d0 + 3) & 7)) * 8 + (key & 7); Vt[o] = vh_; Vl[o] = vl_; }
      }
    }
    __syncthreads();

    const bool diag = (kc == qt);
    // QK^T per 16-key tile -> p -> P planes (wave-private)
#pragma unroll
    for (int j = 0; j < 4; ++j) {
      fx4 sacc = {0.f, 0.f, 0.f, 0.f};
#pragma unroll
      for (int ks = 0; ks < 2; ++ks) {
        const int krow = j * 16 + (lane & 15);
        const int soff = ((ks * 4 + (lane >> 4)) ^ (krow & 7)) * 8;
        const short8 bh = *(const short8*)&Kh[krow * 64 + soff];
        const short8 bl = *(const short8*)&Kl[krow * 64 + soff];
        sacc = __builtin_amdgcn_mfma_f32_16x16x32_bf16(qh[ks], bh, sacc, 0, 0, 0);
        sacc = __builtin_amdgcn_mfma_f32_16x16x32_bf16(ql[ks], bh, sacc, 0, 0, 0);
        sacc = __builtin_amdgcn_mfma_f32_16x16x32_bf16(qh[ks], bl, sacc, 0, 0, 0);
      }
      const int key = c0 + j * 16 + (lane & 15);
      const int am = amask[b * SEQ + key];
      const int col = j * 16 + (lane & 15);
#pragma unroll
      for (int qi = 0; qi < 4; ++qi) {
        const int prow = (lane >> 4) * 4 + qi;
        const int row = qrow0 + prow;
        const float e = __expf(sacc[qi] * 0.25f);
        const float S = 30.f - 60.f / (e + 1.f);   // 30*tanh(s/8), NaN-safe
        float p = __expf(S);
        const bool valid = (!diag || (key <= row)) && (am != 0);
        p = valid ? p : 0.f;
        sumr[qi] += p;
        unsigned short ph_, pl_;
        split2(p, ph_, pl_);
        const int ss = (((col >> 3) ^ (prow & 7)) * 8) + (col & 7);
        Ph[w][prow * 64 + ss] = ph_;
        Pl[w][prow * 64 + ss] = pl_;
      }
    }

    // PV: A = P frags (row = lane&15), B = Vt/Vl frags (row = d)
#pragma unroll
    for (int jd = 0; jd < 4; ++jd) {
#pragma unroll
      for (int ks = 0; ks < 2; ++ks) {
        const int drow = jd * 16 + (lane & 15);
        const int soff = ((ks * 4 + (lane >> 4)) ^ (drow & 7)) * 8;
        const short8 bv  = *(const short8*)&Vt[drow * 64 + soff];
        const short8 bvl = *(const short8*)&Vl[drow * 64 + soff];
        const int psoff = ((ks * 4 + (lane >> 4)) ^ (lane & 7)) * 8;
        const short8 pa = *(const short8*)&Ph[w][(lane & 15) * 64 + psoff];
        const short8 pb = *(const short8*)&Pl[w][(lane & 15) * 64 + psoff];
        oacc[jd] = __builtin_amdgcn_mfma_f32_16x16x32_bf16(pa, bv, oacc[jd], 0, 0, 0);
        oacc[jd] = __builtin_amdgcn_mfma_f32_16x16x32_bf16(pb, bv, oacc[jd], 0, 0, 0);
        oacc[jd] = __builtin_amdgcn_mfma_f32_16x16x32_bf16(pa, bvl, oacc[jd], 0, 0, 0);
      }
    }
  }

  // row-sum reduce over the 16-lane col group, then normalize + write
#pragma unroll
  for (int qi = 0; qi < 4; ++qi) {
    float cs = sumr[qi];
#pragma unroll
    for (int o = 1; o <= 8; o <<= 1) cs += __shfl_xor(cs, o);
    sumr[qi] = cs;
  }
#pragma unroll
  for (int jd = 0; jd < 4; ++jd) {
#pragma unroll
    for (int qi = 0; qi < 4; ++qi) {
      const int row = qrow0 + (lane >> 4) * 4 + qi;
      const int d = jd * 16 + (lane & 15);
      const float o = oacc[jd][qi] / sumr[qi];
      unsigned short hh, ll;
      split2(o, hh, ll);
      out2[(base + row) * 2048 + h * 64 + d] = hh;
      out2[(base + row) * 2048 + 1024 + h * 64 + d] = ll;
    }
  }
}

extern "C" void kernel_launch(void* const* d_in, const int* in_sizes, int n_in,
                              void* d_out, int out_size, void* d_ws, size_t ws_size,
                              hipStream_t stream) {
  const int*   ids       = (const int*)d_in[0];
  const int*   amask     = (const int*)d_in[1];
  const float* W_vocab   = (const float*)d_in[2];
  const float* W_devocab = (const float*)d_in[3];
  const float* WQ        = (const float*)d_in[4];
  const float* WK        = (const float*)d_in[5];
  const float* WV        = (const float*)d_in[6];
  const float* W_O       = (const float*)d_in[7];
  const float* gamma1    = (const float*)d_in[8];
  const float* beta1     = (const float*)d_in[9];
  const float* gamma2    = (const float*)d_in[10];
  const float* beta2     = (const float*)d_in[11];
  const float* W_up      = (const float*)d_in[12];
  const float* b_up      = (const float*)d_in[13];
  const float* W_down    = (const float*)d_in[14];
  const float* b_down    = (const float*)d_in[15];
  const float* gamma_f   = (const float*)d_in[16];
  const float* beta_f    = (const float*)d_in[17];

  char* p = (char*)d_ws;
  auto alloc = [&](size_t bytes) { char* r = p; p += (bytes + 255) & ~(size_t)255; return r; };

  unsigned short* WQKV2 = (unsigned short*)alloc((size_t)NLAYERS * 3072 * 2048 * 2);
  unsigned short* WO2   = (unsigned short*)alloc((size_t)NLAYERS * 1024 * 2048 * 2);
  unsigned short* WUp2  = (unsigned short*)alloc((size_t)NLAYERS * 4096 * 2048 * 2);
  unsigned short* WDn2  = (unsigned short*)alloc((size_t)NLAYERS * 1024 * 8192 * 2);
  unsigned short* WDev1 = (unsigned short*)alloc((size_t)VOCAB * 1024 * 2);
  float* x    = (float*)alloc((size_t)NTOK * 1024 * 4);
  float* z1   = (float*)alloc((size_t)NTOK * 1024 * 4);
  unsigned short* u2    = (unsigned short*)alloc((size_t)NTOK * 2048 * 2);   // also v1 / xf
  float* qkvf = (float*)alloc((size_t)NTOK * 3072 * 4);
  unsigned short* attn2 = (unsigned short*)alloc((size_t)NTOK * 2048 * 2);
  unsigned short* h2    = (unsigned short*)alloc((size_t)NTOK * 8192 * 2);
  (void)ws_size; (void)in_sizes; (void)n_in; (void)out_size;

  // ---- weight prep (hi/lo split planes) ----
  cvt_qkv_split<<<2048, 256, 0, stream>>>(WQ, WK, WV, WQKV2);
  cvt_split<<<2048, 256, 0, stream>>>(W_O, WO2, (long)NLAYERS * 1024, 1024);
  transpose_cvt_split<<<dim3(4096 / 32, 1024 / 32, NLAYERS), 256, 0, stream>>>(W_up, WUp2, 1024, 4096);
  transpose_cvt_split<<<dim3(1024 / 32, 4096 / 32, NLAYERS), 256, 0, stream>>>(W_down, WDn2, 4096, 1024);
  transpose_cvt<<<dim3(VOCAB / 32, 1024 / 32, 1), 256, 0, stream>>>(W_devocab, WDev1, 1024, VOCAB);

  // ---- embedding ----
  embed_kernel<<<NTOK, 256, 0, stream>>>(ids, W_vocab, x);

  // ---- layers ----
  for (int l = 0; l < NLAYERS; ++l) {
    layernorm_split<<<NTOK, 256, 0, stream>>>(x, gamma1 + l * 1024, beta1 + l * 1024, u2);
    // fused QKV (split-3, f32 out): [4096,3072]
    gemm_bt<0, 3, 0><<<dim3(3072 / 128, NTOK / 128), 256, 0, stream>>>(
        u2, WQKV2 + (size_t)l * 3072 * 2048, qkvf, nullptr, nullptr, nullptr,
        NTOK, 3072, 1024);
    attn_kernel<<<BATCH * NHEADS * 8, 256, 0, stream>>>(qkvf, amask, attn2);
    // z1 = x + attn @ W_O^T
    gemm_bt<2, 3, 0><<<dim3(1024 / 128, NTOK / 128), 256, 0, stream>>>(
        attn2, WO2 + (size_t)l * 1024 * 2048, z1, nullptr, nullptr, x,
        NTOK, 1024, 1024);
    layernorm_split<<<NTOK, 256, 0, stream>>>(z1, gamma2 + l * 1024, beta2 + l * 1024, u2);
    // h = gelu(v1 @ W_up + b_up), hi/lo out
    gemm_bt<3, 3, 0><<<dim3(4096 / 128, NTOK / 128), 256, 0, stream>>>(
        u2, WUp2 + (size_t)l * 4096 * 2048, nullptr, h2, b_up + l * 4096, nullptr,
        NTOK, 4096, 1024);
    // x = z1 + h @ W_down + b_down
    gemm_bt<4, 3, 0><<<dim3(1024 / 128, NTOK / 128), 256, 0, stream>>>(
        h2, WDn2 + (size_t)l * 1024 * 8192, x, nullptr, b_down + l * 1024, z1,
        NTOK, 1024, 4096);
  }

  // ---- final LN + devocab (split-2; brow-major grid for B reuse) ----
  layernorm_split<<<NTOK, 256, 0, stream>>>(x, gamma_f, beta_f, u2);
  gemm_bt<0, 2, 1><<<dim3(NTOK / 128, VOCAB / 128), 256, 0, stream>>>(
      u2, WDev1, (float*)d_out, nullptr, nullptr, nullptr,
      NTOK, VOCAB, 1024);
}

// Round 15
// 7986.757 us; speedup vs baseline: 4.9744x; 1.1026x over previous
//
#include <hip/hip_runtime.h>
#include <math.h>

#define D_MODEL 1024
#define NHEADS 16
#define DHEAD 64
#define NLAYERS 12
#define VOCAB 32000
#define BATCH 8
#define SEQ 512
#define NTOK (BATCH*SEQ)   // 4096

using short8 = __attribute__((ext_vector_type(8))) short;
using fx4    = __attribute__((ext_vector_type(4))) float;
using fx16   = __attribute__((ext_vector_type(16))) float;

#define GLL16(g, l) __builtin_amdgcn_global_load_lds( \
    (const __attribute__((address_space(1))) unsigned int*)(g), \
    (__attribute__((address_space(3))) unsigned int*)(l), 16, 0, 0)

__device__ __forceinline__ unsigned short f2bf(float f) {
  union { float f; unsigned u; } v; v.f = f;
  unsigned r = v.u + 0x7FFFu + ((v.u >> 16) & 1u);
  return (unsigned short)(r >> 16);
}
__device__ __forceinline__ float bf2f(unsigned short u) {
  union { unsigned u; float f; } v; v.u = ((unsigned)u) << 16;
  return v.f;
}
__device__ __forceinline__ void split2(float x, unsigned short& h, unsigned short& l) {
  h = f2bf(x);
  l = f2bf(x - bf2f(h));
}
__device__ __forceinline__ float gelu_exact(float x) {
  return 0.5f * x * (1.f + erff(x * 0.70710678118654752f));
}

// ---------------- weight conversion (hi/lo split planes) ----------------

__global__ __launch_bounds__(256) void cvt_qkv_split(const float* __restrict__ WQ,
    const float* __restrict__ WK, const float* __restrict__ WV,
    unsigned short* __restrict__ out)
{
  const long total = 12L * 3072 * 256;     // float4 units
  const long stride = (long)gridDim.x * blockDim.x;
  for (long t = (long)blockIdx.x * blockDim.x + threadIdx.x; t < total; t += stride) {
    const long layer = t / (3072L * 256);
    const long rem = t - layer * (3072L * 256);
    const int n = (int)(rem >> 8);
    const int k4 = (int)(rem & 255);
    const float* src;
    if (n < 1024)       src = WQ + ((size_t)layer * 1024 + n) * 1024;
    else if (n < 2048)  src = WK + ((size_t)layer * 1024 + (n - 1024)) * 1024;
    else                src = WV + ((size_t)layer * 1024 + (n - 2048)) * 1024;
    const float4 v = *(const float4*)(src + k4 * 4);
    ushort4 h, l; unsigned short a, b;
    split2(v.x, a, b); h.x = a; l.x = b;
    split2(v.y, a, b); h.y = a; l.y = b;
    split2(v.z, a, b); h.z = a; l.z = b;
    split2(v.w, a, b); h.w = a; l.w = b;
    unsigned short* dst = out + ((size_t)layer * 3072 + n) * 2048 + k4 * 4;
    *(ushort4*)dst = h;
    *(ushort4*)(dst + 1024) = l;
  }
}

__global__ __launch_bounds__(256) void cvt_split(const float* __restrict__ in,
    unsigned short* __restrict__ out, long rows, int K)
{
  const int K4 = K >> 2;
  const long total = rows * K4;
  const long stride = (long)gridDim.x * blockDim.x;
  for (long t = (long)blockIdx.x * blockDim.x + threadIdx.x; t < total; t += stride) {
    const long r = t / K4;
    const int k4 = (int)(t - r * K4);
    const float4 v = *(const float4*)(in + r * K + k4 * 4);
    ushort4 h, l; unsigned short a, b;
    split2(v.x, a, b); h.x = a; l.x = b;
    split2(v.y, a, b); h.y = a; l.y = b;
    split2(v.z, a, b); h.z = a; l.z = b;
    split2(v.w, a, b); h.w = a; l.w = b;
    unsigned short* dst = out + r * 2 * K + k4 * 4;
    *(ushort4*)dst = h;
    *(ushort4*)(dst + K) = l;
  }
}

__global__ __launch_bounds__(256) void transpose_cvt_split(const float* __restrict__ in,
    unsigned short* __restrict__ out, int R, int C)
{
  __shared__ float tile[32][33];
  in  += (size_t)blockIdx.z * R * C;
  out += (size_t)blockIdx.z * 2 * R * C;
  const int r0 = blockIdx.y * 32, c0 = blockIdx.x * 32;
  const int tr = threadIdx.x >> 5, tc = threadIdx.x & 31;
#pragma unroll
  for (int i = 0; i < 4; ++i)
    tile[tr + i * 8][tc] = in[(size_t)(r0 + tr + i * 8) * C + c0 + tc];
  __syncthreads();
#pragma unroll
  for (int i = 0; i < 4; ++i) {
    unsigned short h, l;
    split2(tile[tc][tr + i * 8], h, l);
    const size_t o = (size_t)(c0 + tr + i * 8) * 2 * R + r0 + tc;
    out[o] = h;
    out[o + R] = l;
  }
}

__global__ __launch_bounds__(256) void transpose_cvt(const float* __restrict__ in,
    unsigned short* __restrict__ out, int R, int C)
{
  __shared__ float tile[32][33];
  const int r0 = blockIdx.y * 32, c0 = blockIdx.x * 32;
  const int tr = threadIdx.x >> 5, tc = threadIdx.x & 31;
#pragma unroll
  for (int i = 0; i < 4; ++i)
    tile[tr + i * 8][tc] = in[(size_t)(r0 + tr + i * 8) * C + c0 + tc];
  __syncthreads();
#pragma unroll
  for (int i = 0; i < 4; ++i)
    out[(size_t)(c0 + tr + i * 8) * R + r0 + tc] = f2bf(tile[tc][tr + i * 8]);
}

// ---------------- embedding + positional ----------------

__global__ __launch_bounds__(256) void embed_kernel(const int* __restrict__ ids,
    const float* __restrict__ Wv, float* __restrict__ x)
{
  const int t = blockIdx.x;
  const int id = ids[t];
  const int l = t & (SEQ - 1);
  const float pos = (float)l;
  const int d0 = threadIdx.x * 4;
  const float i0 = (float)(d0 >> 1);
  const float f0 = expf(-0.017988946039016f * i0);
  const float f1 = expf(-0.017988946039016f * (i0 + 1.f));
  const float a0 = pos * f0, a1 = pos * f1;
  float4 v;
  v.x = Wv[(size_t)(d0 + 0) * VOCAB + id] + sinf(a0);
  v.y = Wv[(size_t)(d0 + 1) * VOCAB + id] + cosf(a0);
  v.z = Wv[(size_t)(d0 + 2) * VOCAB + id] + sinf(a1);
  v.w = Wv[(size_t)(d0 + 3) * VOCAB + id] + cosf(a1);
  ((float4*)(x + (size_t)t * 1024))[threadIdx.x] = v;
}

// ---------------- layernorm (f32 in -> hi/lo bf16 planes out, stride 2048) ----------------

__global__ __launch_bounds__(256) void layernorm_split(const float* __restrict__ x,
    const float* __restrict__ g, const float* __restrict__ be,
    unsigned short* __restrict__ out)
{
  const int row = blockIdx.x;
  const float4 v = ((const float4*)(x + (size_t)row * 1024))[threadIdx.x];
  float s = v.x + v.y + v.z + v.w;
  float q = v.x * v.x + v.y * v.y + v.z * v.z + v.w * v.w;
#pragma unroll
  for (int o = 32; o; o >>= 1) { s += __shfl_xor(s, o); q += __shfl_xor(q, o); }
  __shared__ float ss[4], qq[4];
  const int w = threadIdx.x >> 6;
  if ((threadIdx.x & 63) == 0) { ss[w] = s; qq[w] = q; }
  __syncthreads();
  s = ss[0] + ss[1] + ss[2] + ss[3];
  q = qq[0] + qq[1] + qq[2] + qq[3];
  const float mean = s * (1.f / 1024.f);
  const float var = q * (1.f / 1024.f) - mean * mean;
  const float rstd = rsqrtf(var + 1e-5f);
  const float4 gv = ((const float4*)g)[threadIdx.x];
  const float4 bv = ((const float4*)be)[threadIdx.x];
  float4 y;
  y.x = (v.x - mean) * rstd * gv.x + bv.x;
  y.y = (v.y - mean) * rstd * gv.y + bv.y;
  y.z = (v.z - mean) * rstd * gv.z + bv.z;
  y.w = (v.w - mean) * rstd * gv.w + bv.w;
  ushort4 h4, l4; unsigned short a, b;
  split2(y.x, a, b); h4.x = a; l4.x = b;
  split2(y.y, a, b); h4.y = a; l4.y = b;
  split2(y.z, a, b); h4.z = a; l4.z = b;
  split2(y.w, a, b); h4.w = a; l4.w = b;
  unsigned short* dst = out + (size_t)row * 2048 + threadIdx.x * 4;
  *(ushort4*)dst = h4;
  *(ushort4*)(dst + 1024) = l4;
}

// ---------------- split GEMM: C[M,N] = A[M,K] * B[N,K]^T, near-f32 precision ----------------
// 32x32x16 MFMA + global_load_lds staging + XOR slot-swizzle with
// g(r) = (r&7) ^ ((r>>3)&7): lanes L, L+8, L+16, L+24 (same lane&7, rows differing in
// bits 3-4) now land on distinct slots -> restores the conflict-free 16x16 invariant.
// TN: 128 (default) or 64 (N=1024 GEMMs: doubles block count -> 2 blocks/CU).
// SWAPG=1: brow on fast axis (devocab B-panel L2 reuse).

template<int EPI, int SPLIT, int SWAPG, int TN>
__global__ __launch_bounds__(256) void gemm_bt(
    const unsigned short* __restrict__ A, const unsigned short* __restrict__ B,
    float* __restrict__ Cf, unsigned short* __restrict__ Cb,
    const float* __restrict__ bias, const float* __restrict__ res,
    int M, int N, int K)
{
  __shared__ __align__(16) unsigned short As[128 * 64];
  __shared__ __align__(16) unsigned short Bs[TN * 64];
  const int NJ = TN / 64;                       // tj extent (wave col-tiles of 32)
  const int tid = threadIdx.x;
  const int lane = tid & 63, w = tid >> 6;
  const int wr = w >> 1, wc = w & 1;
  const int bxi = SWAPG ? blockIdx.y : blockIdx.x;
  const int byi = SWAPG ? blockIdx.x : blockIdx.y;
  const int brow = byi * 128, bcol = bxi * TN;

  const int SA = 2 * K;                         // A always hi/lo
  const int SB = (SPLIT == 3) ? 2 * K : K;
  const int KEFF = SPLIT * K;
  fx16 acc[2][2];
#pragma unroll
  for (int i = 0; i < 2; ++i)
#pragma unroll
    for (int j = 0; j < 2; ++j)
#pragma unroll
      for (int e = 0; e < 16; ++e) acc[i][j][e] = 0.f;

  const unsigned short* Ab = A + (size_t)brow * SA;
  const unsigned short* Bb = B + (size_t)bcol * SB;

  const int l31 = lane & 31, l7 = lane & 7, t3 = l31 >> 3;

  for (int k0 = 0; k0 < KEFF; k0 += 64) {
    int ka, kb;
    if (SPLIT == 3) {
      ka = (k0 < 2 * K) ? k0 : k0 - 2 * K;      // hi | lo | hi
      kb = (k0 < K) ? k0 : k0 - K;              // hi | hi | lo
    } else {
      ka = k0;                                  // hi | lo
      kb = (k0 < K) ? k0 : k0 - K;              // hi | hi
    }
    const unsigned short* Aseg = Ab + ka;
    const unsigned short* Bseg = Bb + kb;
#pragma unroll
    for (int it = 0; it < 4; ++it) {
      const int idx = it * 256 + tid;          // 0..1023
      const int r = idx >> 3;                  // tile row
      const int c = (((idx & 7) ^ (r & 7)) ^ ((r >> 3) & 7)) * 8;  // pre-swizzled src slot
      GLL16(&Aseg[(size_t)r * SA + c], &As[idx * 8]);
      if (it < TN / 32)
        GLL16(&Bseg[(size_t)r * SB + c], &Bs[idx * 8]);
    }
    __syncthreads();   // drains vmcnt (global_load_lds) before ds_read
#pragma unroll
    for (int ks = 0; ks < 4; ++ks) {           // K = 4 x 16
      const int Sb = ks * 2 + (lane >> 5);     // logical 16B slot
      short8 af[2], bfv[2];
#pragma unroll
      for (int ti = 0; ti < 2; ++ti) {
        const int gA = l7 ^ ((ti * 4 + t3) & 7);
        af[ti] = *(const short8*)&As[(wr * 64 + ti * 32 + l31) * 64 + (Sb ^ gA) * 8];
      }
#pragma unroll
      for (int tj = 0; tj < NJ; ++tj) {
        const int gB = l7 ^ (((wc * (TN / 16)) + tj * 4 + t3) & 7);
        bfv[tj] = *(const short8*)&Bs[(wc * (TN / 2) + tj * 32 + l31) * 64 + (Sb ^ gB) * 8];
      }
#pragma unroll
      for (int ti = 0; ti < 2; ++ti)
#pragma unroll
        for (int tj = 0; tj < NJ; ++tj)
          acc[ti][tj] = __builtin_amdgcn_mfma_f32_32x32x16_bf16(af[ti], bfv[tj], acc[ti][tj], 0, 0, 0);
    }
    __syncthreads();
  }

  // C/D: col = lane&31, row = (reg&3) + 8*(reg>>2) + 4*(lane>>5)
  const int cl = lane & 31;
  const int rb = 4 * (lane >> 5);
#pragma unroll
  for (int ti = 0; ti < 2; ++ti) {
#pragma unroll
    for (int tj = 0; tj < NJ; ++tj) {
      const int cc = bcol + wc * (TN / 2) + tj * 32 + cl;
#pragma unroll
      for (int reg = 0; reg < 16; ++reg) {
        const int rr = brow + wr * 64 + ti * 32 + (reg & 3) + 8 * (reg >> 2) + rb;
        const size_t off = (size_t)rr * N + cc;
        const float val = acc[ti][tj][reg];
        if (EPI == 0) {
          Cf[off] = val;
        } else if (EPI == 2) {
          Cf[off] = res[off] + val;
        } else if (EPI == 3) {
          unsigned short hh, ll;
          split2(gelu_exact(val + bias[cc]), hh, ll);
          Cb[(size_t)rr * (2 * N) + cc] = hh;
          Cb[(size_t)rr * (2 * N) + N + cc] = ll;
        } else {
          Cf[off] = res[off] + val + bias[cc];
        }
      }
    }
  }
}

// ---------------- attention v7: MFMA flash + V hi/lo (unchanged from round 14) ----------------

__global__ __launch_bounds__(256, 3) void attn_kernel(
    const float* __restrict__ qkvf,
    const int* __restrict__ amask,
    unsigned short* __restrict__ out2)
{
  const int bid = blockIdx.x;
  const int qt = 7 - (bid & 7);            // heavy causal tiles dispatch first
  const int h  = (bid >> 3) & 15;
  const int b  = bid >> 7;

  __shared__ __align__(16) unsigned short Kh[64 * 64];
  __shared__ __align__(16) unsigned short Kl[64 * 64];
  __shared__ __align__(16) unsigned short Vt[64 * 64];      // [d][key] hi
  __shared__ __align__(16) unsigned short Vl[64 * 64];      // [d][key] lo
  __shared__ __align__(16) unsigned short Ph[4][16 * 64];   // wave-private [row][key]
  __shared__ __align__(16) unsigned short Pl[4][16 * 64];

  const int tid = threadIdx.x, lane = tid & 63, w = tid >> 6;
  const size_t base = (size_t)b * SEQ;
  const int qrow0 = qt * 64 + w * 16;

  short8 qh[2], ql[2];
  {
    const int row = qrow0 + (lane & 15);
    const float* qp = &qkvf[(base + row) * 3072 + h * 64 + (lane >> 4) * 8];
#pragma unroll
    for (int ks = 0; ks < 2; ++ks) {
      const float4 a = *(const float4*)(qp + ks * 32);
      const float4 c = *(const float4*)(qp + ks * 32 + 4);
      short8 hh, ll; unsigned short th, tl;
      split2(a.x, th, tl); hh[0] = (short)th; ll[0] = (short)tl;
      split2(a.y, th, tl); hh[1] = (short)th; ll[1] = (short)tl;
      split2(a.z, th, tl); hh[2] = (short)th; ll[2] = (short)tl;
      split2(a.w, th, tl); hh[3] = (short)th; ll[3] = (short)tl;
      split2(c.x, th, tl); hh[4] = (short)th; ll[4] = (short)tl;
      split2(c.y, th, tl); hh[5] = (short)th; ll[5] = (short)tl;
      split2(c.z, th, tl); hh[6] = (short)th; ll[6] = (short)tl;
      split2(c.w, th, tl); hh[7] = (short)th; ll[7] = (short)tl;
      qh[ks] = hh; ql[ks] = ll;
    }
  }

  fx4 oacc[4];
  float sumr[4] = {0.f, 0.f, 0.f, 0.f};
#pragma unroll
  for (int j = 0; j < 4; ++j) oacc[j] = (fx4){0.f, 0.f, 0.f, 0.f};

  for (int kc = 0; kc <= qt; ++kc) {
    const int c0 = kc * 64;
    __syncthreads();                        // prev chunk fully consumed
#pragma unroll
    for (int it = 0; it < 4; ++it) {        // stage K hi/lo + V^T hi/lo (coalesced reads)
      const int idx = it * 256 + tid;       // 1024 = 64 keys x 16 c4
      const int key = idx >> 4, c4 = idx & 15;
      const float4 kv = *(const float4*)&qkvf[(base + c0 + key) * 3072 + 1024 + h * 64 + c4 * 4];
      ushort4 kh4, kl4;
      split2(kv.x, kh4.x, kl4.x); split2(kv.y, kh4.y, kl4.y);
      split2(kv.z, kh4.z, kl4.z); split2(kv.w, kh4.w, kl4.w);
      const int sl = (((c4 >> 1) ^ (key & 7)) * 8 + (c4 & 1) * 4);
      *(ushort4*)&Kh[key * 64 + sl] = kh4;
      *(ushort4*)&Kl[key * 64 + sl] = kl4;
      const float4 vv = *(const float4*)&qkvf[(base + c0 + key) * 3072 + 2048 + h * 64 + c4 * 4];
      {
        const int d0 = c4 * 4;
        unsigned short vh_, vl_;
        split2(vv.x, vh_, vl_);
        { const int o = (d0 + 0) * 64 + ((key >> 3) ^ ((d0 + 0) & 7)) * 8 + (key & 7); Vt[o] = vh_; Vl[o] = vl_; }
        split2(vv.y, vh_, vl_);
        { const int o = (d0 + 1) * 64 + ((key >> 3) ^ ((d0 + 1) & 7)) * 8 + (key & 7); Vt[o] = vh_; Vl[o] = vl_; }
        split2(vv.z, vh_, vl_);
        { const int o = (d0 + 2) * 64 + ((key >> 3) ^ ((d0 + 2) & 7)) * 8 + (key & 7); Vt[o] = vh_; Vl[o] = vl_; }
        split2(vv.w, vh_, vl_);
        { const int o = (d0 + 3) * 64 + ((key >> 3) ^ ((d0 + 3) & 7)) * 8 + (key & 7); Vt[o] = vh_; Vl[o] = vl_; }
      }
    }
    __syncthreads();

    const bool diag = (kc == qt);
#pragma unroll
    for (int j = 0; j < 4; ++j) {
      fx4 sacc = {0.f, 0.f, 0.f, 0.f};
#pragma unroll
      for (int ks = 0; ks < 2; ++ks) {
        const int krow = j * 16 + (lane & 15);
        const int soff = ((ks * 4 + (lane >> 4)) ^ (krow & 7)) * 8;
        const short8 bh = *(const short8*)&Kh[krow * 64 + soff];
        const short8 bl = *(const short8*)&Kl[krow * 64 + soff];
        sacc = __builtin_amdgcn_mfma_f32_16x16x32_bf16(qh[ks], bh, sacc, 0, 0, 0);
        sacc = __builtin_amdgcn_mfma_f32_16x16x32_bf16(ql[ks], bh, sacc, 0, 0, 0);
        sacc = __builtin_amdgcn_mfma_f32_16x16x32_bf16(qh[ks], bl, sacc, 0, 0, 0);
      }
      const int key = c0 + j * 16 + (lane & 15);
      const int am = amask[b * SEQ + key];
      const int col = j * 16 + (lane & 15);
#pragma unroll
      for (int qi = 0; qi < 4; ++qi) {
        const int prow = (lane >> 4) * 4 + qi;
        const int row = qrow0 + prow;
        const float e = __expf(sacc[qi] * 0.25f);
        const float S = 30.f - 60.f / (e + 1.f);   // 30*tanh(s/8), NaN-safe
        float p = __expf(S);
        const bool valid = (!diag || (key <= row)) && (am != 0);
        p = valid ? p : 0.f;
        sumr[qi] += p;
        unsigned short ph_, pl_;
        split2(p, ph_, pl_);
        const int ss = (((col >> 3) ^ (prow & 7)) * 8) + (col & 7);
        Ph[w][prow * 64 + ss] = ph_;
        Pl[w][prow * 64 + ss] = pl_;
      }
    }

#pragma unroll
    for (int jd = 0; jd < 4; ++jd) {
#pragma unroll
      for (int ks = 0; ks < 2; ++ks) {
        const int drow = jd * 16 + (lane & 15);
        const int soff = ((ks * 4 + (lane >> 4)) ^ (drow & 7)) * 8;
        const short8 bv  = *(const short8*)&Vt[drow * 64 + soff];
        const short8 bvl = *(const short8*)&Vl[drow * 64 + soff];
        const int psoff = ((ks * 4 + (lane >> 4)) ^ (lane & 7)) * 8;
        const short8 pa = *(const short8*)&Ph[w][(lane & 15) * 64 + psoff];
        const short8 pb = *(const short8*)&Pl[w][(lane & 15) * 64 + psoff];
        oacc[jd] = __builtin_amdgcn_mfma_f32_16x16x32_bf16(pa, bv, oacc[jd], 0, 0, 0);
        oacc[jd] = __builtin_amdgcn_mfma_f32_16x16x32_bf16(pb, bv, oacc[jd], 0, 0, 0);
        oacc[jd] = __builtin_amdgcn_mfma_f32_16x16x32_bf16(pa, bvl, oacc[jd], 0, 0, 0);
      }
    }
  }

#pragma unroll
  for (int qi = 0; qi < 4; ++qi) {
    float cs = sumr[qi];
#pragma unroll
    for (int o = 1; o <= 8; o <<= 1) cs += __shfl_xor(cs, o);
    sumr[qi] = cs;
  }
#pragma unroll
  for (int jd = 0; jd < 4; ++jd) {
#pragma unroll
    for (int qi = 0; qi < 4; ++qi) {
      const int row = qrow0 + (lane >> 4) * 4 + qi;
      const int d = jd * 16 + (lane & 15);
      const float o = oacc[jd][qi] / sumr[qi];
      unsigned short hh, ll;
      split2(o, hh, ll);
      out2[(base + row) * 2048 + h * 64 + d] = hh;
      out2[(base + row) * 2048 + 1024 + h * 64 + d] = ll;
    }
  }
}

extern "C" void kernel_launch(void* const* d_in, const int* in_sizes, int n_in,
                              void* d_out, int out_size, void* d_ws, size_t ws_size,
                              hipStream_t stream) {
  const int*   ids       = (const int*)d_in[0];
  const int*   amask     = (const int*)d_in[1];
  const float* W_vocab   = (const float*)d_in[2];
  const float* W_devocab = (const float*)d_in[3];
  const float* WQ        = (const float*)d_in[4];
  const float* WK        = (const float*)d_in[5];
  const float* WV        = (const float*)d_in[6];
  const float* W_O       = (const float*)d_in[7];
  const float* gamma1    = (const float*)d_in[8];
  const float* beta1     = (const float*)d_in[9];
  const float* gamma2    = (const float*)d_in[10];
  const float* beta2     = (const float*)d_in[11];
  const float* W_up      = (const float*)d_in[12];
  const float* b_up      = (const float*)d_in[13];
  const float* W_down    = (const float*)d_in[14];
  const float* b_down    = (const float*)d_in[15];
  const float* gamma_f   = (const float*)d_in[16];
  const float* beta_f    = (const float*)d_in[17];

  char* p = (char*)d_ws;
  auto alloc = [&](size_t bytes) { char* r = p; p += (bytes + 255) & ~(size_t)255; return r; };

  unsigned short* WQKV2 = (unsigned short*)alloc((size_t)NLAYERS * 3072 * 2048 * 2);
  unsigned short* WO2   = (unsigned short*)alloc((size_t)NLAYERS * 1024 * 2048 * 2);
  unsigned short* WUp2  = (unsigned short*)alloc((size_t)NLAYERS * 4096 * 2048 * 2);
  unsigned short* WDn2  = (unsigned short*)alloc((size_t)NLAYERS * 1024 * 8192 * 2);
  unsigned short* WDev1 = (unsigned short*)alloc((size_t)VOCAB * 1024 * 2);
  float* x    = (float*)alloc((size_t)NTOK * 1024 * 4);
  float* z1   = (float*)alloc((size_t)NTOK * 1024 * 4);
  unsigned short* u2    = (unsigned short*)alloc((size_t)NTOK * 2048 * 2);   // also v1 / xf
  float* qkvf = (float*)alloc((size_t)NTOK * 3072 * 4);
  unsigned short* attn2 = (unsigned short*)alloc((size_t)NTOK * 2048 * 2);
  unsigned short* h2    = (unsigned short*)alloc((size_t)NTOK * 8192 * 2);
  (void)ws_size; (void)in_sizes; (void)n_in; (void)out_size;

  // ---- weight prep (hi/lo split planes) ----
  cvt_qkv_split<<<2048, 256, 0, stream>>>(WQ, WK, WV, WQKV2);
  cvt_split<<<2048, 256, 0, stream>>>(W_O, WO2, (long)NLAYERS * 1024, 1024);
  transpose_cvt_split<<<dim3(4096 / 32, 1024 / 32, NLAYERS), 256, 0, stream>>>(W_up, WUp2, 1024, 4096);
  transpose_cvt_split<<<dim3(1024 / 32, 4096 / 32, NLAYERS), 256, 0, stream>>>(W_down, WDn2, 4096, 1024);
  transpose_cvt<<<dim3(VOCAB / 32, 1024 / 32, 1), 256, 0, stream>>>(W_devocab, WDev1, 1024, VOCAB);

  // ---- embedding ----
  embed_kernel<<<NTOK, 256, 0, stream>>>(ids, W_vocab, x);

  // ---- layers ----
  for (int l = 0; l < NLAYERS; ++l) {
    layernorm_split<<<NTOK, 256, 0, stream>>>(x, gamma1 + l * 1024, beta1 + l * 1024, u2);
    // fused QKV (split-3, f32 out): [4096,3072]
    gemm_bt<0, 3, 0, 128><<<dim3(3072 / 128, NTOK / 128), 256, 0, stream>>>(
        u2, WQKV2 + (size_t)l * 3072 * 2048, qkvf, nullptr, nullptr, nullptr,
        NTOK, 3072, 1024);
    attn_kernel<<<BATCH * NHEADS * 8, 256, 0, stream>>>(qkvf, amask, attn2);
    // z1 = x + attn @ W_O^T  (TN=64: 512 blocks -> 2/CU)
    gemm_bt<2, 3, 0, 64><<<dim3(1024 / 64, NTOK / 128), 256, 0, stream>>>(
        attn2, WO2 + (size_t)l * 1024 * 2048, z1, nullptr, nullptr, x,
        NTOK, 1024, 1024);
    layernorm_split<<<NTOK, 256, 0, stream>>>(z1, gamma2 + l * 1024, beta2 + l * 1024, u2);
    // h = gelu(v1 @ W_up + b_up), hi/lo out
    gemm_bt<3, 3, 0, 128><<<dim3(4096 / 128, NTOK / 128), 256, 0, stream>>>(
        u2, WUp2 + (size_t)l * 4096 * 2048, nullptr, h2, b_up + l * 4096, nullptr,
        NTOK, 4096, 1024);
    // x = z1 + h @ W_down + b_down  (TN=64)
    gemm_bt<4, 3, 0, 64><<<dim3(1024 / 64, NTOK / 128), 256, 0, stream>>>(
        h2, WDn2 + (size_t)l * 1024 * 8192, x, nullptr, b_down + l * 1024, z1,
        NTOK, 1024, 4096);
  }

  // ---- final LN + devocab (split-2; brow-major grid for B reuse) ----
  layernorm_split<<<NTOK, 256, 0, stream>>>(x, gamma_f, beta_f, u2);
  gemm_bt<0, 2, 1, 128><<<dim3(NTOK / 128, VOCAB / 128), 256, 0, stream>>>(
      u2, WDev1, (float*)d_out, nullptr, nullptr, nullptr,
      NTOK, VOCAB, 1024);
}